// Round 6
// baseline (839.325 us; speedup 1.0000x reference)
//
#include <hip/hip_runtime.h>
#include <cstddef>
#include <cstdint>

#define LEAKY(x) ((x) > 0.f ? (x) : 0.2f*(x))

typedef _Float16 f16x8  __attribute__((ext_vector_type(8)));
typedef float    f32x16 __attribute__((ext_vector_type(16)));

// ws float-offsets
#define WS_FEATS   0            // 32*64*128 = 262144 floats
#define WS_SCORES  262144       // 2048
#define WS_RES     264192       // 4096
#define WS_W2      268288       // fp16: 2ch*2pl*64*152 = 38912 halfs (19456 float slots)
#define WS_W1P     287744       // 576 floats

// async global->LDS, 16B per lane; LDS dest = wave-uniform base + lane*16
__device__ __forceinline__ void gll16(const void* g, void* l) {
    __builtin_amdgcn_global_load_lds(
        (const __attribute__((address_space(1))) unsigned int*)g,
        (__attribute__((address_space(3))) unsigned int*)l, 16, 0, 0);
}

// ---------------------------------------------------------------------------
// Pre-kernel (16 blocks x 256): pack conv2 weights fp16 hi/lo,
// W2[chunk][plane][co][152], k = tap*16 + ci_in_chunk (k>=144 zero).
// Row stride 152 halfs = 19 granules (odd) -> B-reads cover all 8 LDS slots.
// Also pack conv1 weights [grun][ci][kh][c*3+kw] for uniform s_load.
// ---------------------------------------------------------------------------
__global__ void kPack(const float* __restrict__ c1w, const float* __restrict__ c2w,
                      float* __restrict__ ws)
{
    _Float16* W2 = (_Float16*)(ws + WS_W2);
    float* w1p = ws + WS_W1P;
    const int t = blockIdx.x*256 + threadIdx.x;
    for (int i = t; i < 2*64*152; i += 16*256) {
        int k = i % 152, rest = i / 152;
        int co = rest & 63, c = rest >> 6;
        _Float16 h = (_Float16)0.f, lo = (_Float16)0.f;
        if (k < 144) {
            int tap = k >> 4, cil = k & 15;
            float wv = c2w[(co*32 + c*16 + cil)*9 + tap];
            h  = (_Float16)wv;
            lo = (_Float16)(wv - (float)h);
        }
        W2[((size_t)(c*2 + 0)*64 + co)*152 + k] = h;
        W2[((size_t)(c*2 + 1)*64 + co)*152 + k] = lo;
    }
    if (blockIdx.x == 0) {
        for (int i = threadIdx.x; i < 576; i += 256) {
            int kw = i % 3; int r = i / 3;
            int c = r & 7; r >>= 3;
            int kh = r % 3; r /= 3;
            int ci = r & 1; int grun = r >> 1;
            int co = grun*8 + c;
            w1p[i] = c1w[co*18 + ci*9 + kh*3 + kw];
        }
    }
}

// ---------------------------------------------------------------------------
// Kernel A: per image n (2048 blocks x 1024 thr = 16 waves)
//   conv1 fp32 VALU -> x1 NHWC fp16 hi/lo in LDS
//   conv2 implicit-GEMM v_mfma_f32_32x32x16_f16, 2-term split (3 MFMA/tap)
//   GAP -> proj -> scorer MLP -> score (fp32, 8-way K-split epilogue)
// B-chunks + input staged via global_load_lds (async, hidden under conv1).
// NOTE: bare __launch_bounds__(1024) — round-5's (1024,4) made the allocator
// clamp to 64 VGPR and spill ~900 B/thread to scratch (1.9 GB HBM writes,
// MfmaUtil 0.3%). Do not re-add a second arg here.
// ---------------------------------------------------------------------------
__global__ __launch_bounds__(1024) void kA(
    const float* __restrict__ texts, const float* __restrict__ styles,
    const float* __restrict__ c1b, const float* __restrict__ c2b,
    const float* __restrict__ pw,  const float* __restrict__ pb,
    const float* __restrict__ v1w, const float* __restrict__ v1b,
    const float* __restrict__ v2w, const float* __restrict__ v2b,
    const float* __restrict__ v3w, const float* __restrict__ v3b,
    const float* __restrict__ wsro,
    float* __restrict__ feats, float* __restrict__ scores)
{
    __shared__ __align__(16) float    s_in[2][65][64];   // rows 0-63 data, row 64 zero
    __shared__ __align__(16) _Float16 s_x1[2][33*33*16]; // hi, lo
    __shared__ __align__(16) _Float16 s_B[2][64*152];    // hi, lo (one ci-chunk)
    __shared__ float s_part[8][64];
    __shared__ float s_red2[8][128];
    __shared__ float s_gap[64], s_f[128], s_h[128], s_red[2];

    const int n = blockIdx.x, tid = threadIdx.x;
    const int w = tid >> 6, l = tid & 63;

    const char* W2c = (const char*)(wsro + WS_W2);  // 2 chunks x 38912 B
    char* sB = (char*)&s_B[0][0];

    // ---- issue async staging: B chunk 0 (2432 x16B) + both input channels ----
    gll16(W2c + (size_t)tid*16,        sB + (size_t)tid*16);
    gll16(W2c + (size_t)(tid+1024)*16, sB + (size_t)(tid+1024)*16);
    if (tid < 384)  // 6 full waves
        gll16(W2c + (size_t)(tid+2048)*16, sB + (size_t)(tid+2048)*16);
    gll16((const char*)(texts  + (size_t)n*4096) + (size_t)tid*16,
          (char*)&s_in[0][0][0] + (size_t)tid*16);
    gll16((const char*)(styles + (size_t)n*4096) + (size_t)tid*16,
          (char*)&s_in[1][0][0] + (size_t)tid*16);

    // zero pads while loads fly
    if (tid < 64) s_in[0][64][tid] = 0.f;
    else if (tid < 128) s_in[1][64][tid - 64] = 0.f;
    {
        uint32_t* z = (uint32_t*)&s_x1[0][0];
        for (int i = tid; i < 17424; i += 1024) z[i] = 0u;  // both planes
    }
    __syncthreads();   // drains vmcnt: B0 + inputs resident

    f32x16 acc;
    #pragma unroll
    for (int r = 0; r < 16; ++r) acc[r] = 0.f;

    for (int ch = 0; ch < 2; ++ch) {
        if (ch == 1) {  // s_B free (post-barrier); hide B1 under conv1(1)
            gll16(W2c + 38912 + (size_t)tid*16,        sB + (size_t)tid*16);
            gll16(W2c + 38912 + (size_t)(tid+1024)*16, sB + (size_t)(tid+1024)*16);
            if (tid < 384)
                gll16(W2c + 38912 + (size_t)(tid+2048)*16, sB + (size_t)(tid+2048)*16);
        }

        // ---- conv1: c_out [ch*16, ch*16+16), 2 runs x 8 c_out ----
        {
            const int run = tid >> 9;            // wave-uniform
            const int t9  = tid & 511;
            const int coB = ch*16 + run*8;
            float a[2][8];
            #pragma unroll
            for (int c = 0; c < 8; ++c) {
                float b1 = c1b[coB + c];
                a[0][c] = b1; a[1][c] = b1;
            }
            const float* w1pg = wsro + WS_W1P + (ch*2 + run)*144;
            #pragma unroll
            for (int ci = 0; ci < 2; ++ci)
            #pragma unroll
            for (int kh = 0; kh < 3; ++kh) {
                const float* wrow = w1pg + (ci*3 + kh)*24;
                float wv[24];
                #pragma unroll
                for (int q = 0; q < 6; ++q)
                    *(float4*)&wv[q*4] = *(const float4*)&wrow[q*4];  // uniform -> s_load
                #pragma unroll
                for (int p = 0; p < 2; ++p) {
                    const int pos = t9 + p*512, py = pos >> 5, px = pos & 31;
                    const float* row = &s_in[ci][2*py + kh][2*px];
                    float2 i01 = *(const float2*)row;
                    float  i2  = (px < 31) ? row[2] : 0.f;   // SAME right-pad
                    #pragma unroll
                    for (int c = 0; c < 8; ++c)
                        a[p][c] += wv[c*3]*i01.x + wv[c*3+1]*i01.y + wv[c*3+2]*i2;
                }
            }
            #pragma unroll
            for (int p = 0; p < 2; ++p) {
                const int pos = t9 + p*512, py = pos >> 5, px = pos & 31;
                const int xs = px ^ ((px >> 1) & 1);         // granule-slot swizzle
                const int eo = (py*33 + xs)*16 + run*8;
                _Float16 hh[8], ll[8];
                #pragma unroll
                for (int c = 0; c < 8; ++c) {
                    float v = LEAKY(a[p][c]);
                    _Float16 h = (_Float16)v;
                    hh[c] = h; ll[c] = (_Float16)(v - (float)h);
                }
                *(uint4*)&s_x1[0][eo] = *(uint4*)hh;
                *(uint4*)&s_x1[1][eo] = *(uint4*)ll;
            }
        }
        __syncthreads();   // x1 ready; (ch==1) also drains B1

        // ---- conv2: 16 waves = 8 M-tiles x 2 N-halves, 27 MFMA each ----
        {
            const int mt = w >> 1, nh = w & 1;
            const int pos = mt*32 + (l & 31);
            const int py = pos >> 4, px = pos & 15;
            const int hf = l >> 5;
            const int cob = nh*32 + (l & 31);
            #pragma unroll
            for (int tap = 0; tap < 9; ++tap) {
                const int kh = tap/3, kw = tap%3;
                const int xr = 2*px + kw;
                const int xs = xr ^ ((xr >> 1) & 1);
                const int ae = ((2*py + kh)*33 + xs)*16 + hf*8;
                f16x8 Ah = *(const f16x8*)&s_x1[0][ae];
                f16x8 Al = *(const f16x8*)&s_x1[1][ae];
                const int be = cob*152 + tap*16 + hf*8;
                f16x8 Bh = *(const f16x8*)&s_B[0][be];
                f16x8 Bl = *(const f16x8*)&s_B[1][be];
                acc = __builtin_amdgcn_mfma_f32_32x32x16_f16(Ah, Bh, acc, 0, 0, 0);
                acc = __builtin_amdgcn_mfma_f32_32x32x16_f16(Ah, Bl, acc, 0, 0, 0);
                acc = __builtin_amdgcn_mfma_f32_32x32x16_f16(Al, Bh, acc, 0, 0, 0);
            }
        }
        __syncthreads();   // s_B / s_x1 consumed; safe to restage
    }

    // ---- bias + leaky + GAP (sum all acc regs + both lane halves) ----
    {
        const int mt = w >> 1, nh = w & 1;
        const float b2 = c2b[nh*32 + (l & 31)];
        float s = 0.f;
        #pragma unroll
        for (int r = 0; r < 16; ++r) s += LEAKY(acc[r] + b2);
        s += __shfl_xor(s, 32);
        if (l < 32) s_part[mt][nh*32 + l] = s;
    }
    __syncthreads();
    if (tid < 64) {
        float s = 0.f;
        #pragma unroll
        for (int mt = 0; mt < 8; ++mt) s += s_part[mt][tid];
        s_gap[tid] = s * (1.f/256.f);
    }
    __syncthreads();

    // ---- proj + scorer: 128 outputs x 8-way K-split ----
    const int j = tid & 127, ks = tid >> 7;
    {
        float p = 0.f;
        #pragma unroll
        for (int m = ks*8; m < ks*8 + 8; ++m) p += s_gap[m]*pw[m*128 + j];
        s_red2[ks][j] = p;
    }
    __syncthreads();
    if (tid < 128) {
        float a = pb[tid];
        #pragma unroll
        for (int q = 0; q < 8; ++q) a += s_red2[q][tid];
        feats[(size_t)n*128 + tid] = a;
        s_f[tid] = a;
    }
    __syncthreads();
    {
        float p = 0.f;
        #pragma unroll
        for (int m = ks*16; m < ks*16 + 16; ++m) p += s_f[m]*v1w[m*128 + j];
        s_red2[ks][j] = p;
    }
    __syncthreads();
    if (tid < 128) {
        float a = v1b[tid];
        #pragma unroll
        for (int q = 0; q < 8; ++q) a += s_red2[q][tid];
        s_h[tid] = LEAKY(a);
    }
    __syncthreads();
    {
        float p = 0.f;
        #pragma unroll
        for (int m = ks*16; m < ks*16 + 16; ++m) p += s_h[m]*v2w[m*128 + j];
        s_red2[ks][j] = p;
    }
    __syncthreads();
    if (tid < 128) {
        float a = v2b[tid];
        #pragma unroll
        for (int q = 0; q < 8; ++q) a += s_red2[q][tid];
        a = LEAKY(a);
        s_f[tid] = a * v3w[tid];
    }
    __syncthreads();
    if (tid < 128) {
        float p = s_f[tid];
        #pragma unroll
        for (int off = 32; off; off >>= 1) p += __shfl_xor(p, off);
        if ((tid & 63) == 0) s_red[tid >> 6] = p;
    }
    __syncthreads();
    if (tid == 0) scores[n] = tanhf(s_red[0] + s_red[1] + v3b[0]);
}

// ---------------------------------------------------------------------------
// Kernel B: per-batch argmax (first-index tie-break) + gather feats row
// ---------------------------------------------------------------------------
__global__ __launch_bounds__(128) void kArgGather(
    const float* __restrict__ scores, const float* __restrict__ feats,
    float* __restrict__ res)
{
    __shared__ int s_idx;
    const int b = blockIdx.x, tid = threadIdx.x;
    if (tid < 64) {
        float v = scores[b*64 + tid];
        int   i = tid;
        #pragma unroll
        for (int off = 32; off; off >>= 1) {
            float ov = __shfl_xor(v, off);
            int   oi = __shfl_xor(i, off);
            if (ov > v || (ov == v && oi < i)) { v = ov; i = oi; }
        }
        if (tid == 0) s_idx = i;
    }
    __syncthreads();
    const int idx = s_idx;
    res[b*128 + tid] = feats[((size_t)b*64 + idx)*128 + tid];
}

// ---------------------------------------------------------------------------
// Kernel C: decoder (fp32). bid%8 -> same d2 column slice per XCD.
// ---------------------------------------------------------------------------
__global__ __launch_bounds__(512) void kDecode(
    const float* __restrict__ res,
    const float* __restrict__ d1w, const float* __restrict__ d1b,
    const float* __restrict__ d2w, const float* __restrict__ d2b,
    float* __restrict__ out)
{
    __shared__ float s_res[128];
    __shared__ float s_h[512];
    const int bid = blockIdx.x;
    const int b = bid >> 3, ot = bid & 7;
    const int tid = threadIdx.x;

    if (tid < 128) s_res[tid] = res[b*128 + tid];
    __syncthreads();
    {
        float a = d1b[tid];
        #pragma unroll 8
        for (int m = 0; m < 128; ++m) a += s_res[m]*d1w[m*512 + tid];
        s_h[tid] = LEAKY(a);
    }
    __syncthreads();
    const int o = ot*512 + tid;
    float a = d2b[o];
    for (int k = 0; k < 512; k += 4) {
        float4 h4 = *(const float4*)&s_h[k];
        a += h4.x*d2w[(size_t)(k+0)*4096 + o];
        a += h4.y*d2w[(size_t)(k+1)*4096 + o];
        a += h4.z*d2w[(size_t)(k+2)*4096 + o];
        a += h4.w*d2w[(size_t)(k+3)*4096 + o];
    }
    out[(size_t)b*4096 + o] = tanhf(a);
}

// ---------------------------------------------------------------------------
extern "C" void kernel_launch(void* const* d_in, const int* in_sizes, int n_in,
                              void* d_out, int out_size, void* d_ws, size_t ws_size,
                              hipStream_t stream)
{
    const float* texts  = (const float*)d_in[0];
    const float* styles = (const float*)d_in[1];
    const float* c1w = (const float*)d_in[2];
    const float* c1b = (const float*)d_in[3];
    const float* c2w = (const float*)d_in[4];
    const float* c2b = (const float*)d_in[5];
    const float* pw  = (const float*)d_in[6];
    const float* pb  = (const float*)d_in[7];
    const float* v1w = (const float*)d_in[8];
    const float* v1b = (const float*)d_in[9];
    const float* v2w = (const float*)d_in[10];
    const float* v2b = (const float*)d_in[11];
    const float* v3w = (const float*)d_in[12];
    const float* v3b = (const float*)d_in[13];
    const float* d1w = (const float*)d_in[14];
    const float* d1b = (const float*)d_in[15];
    const float* d2w = (const float*)d_in[16];
    const float* d2b = (const float*)d_in[17];

    float* ws     = (float*)d_ws;
    float* feats  = ws + WS_FEATS;
    float* scores = ws + WS_SCORES;
    float* res    = ws + WS_RES;

    kPack<<<dim3(16), dim3(256), 0, stream>>>(c1w, c2w, ws);
    kA<<<dim3(2048), dim3(1024), 0, stream>>>(
        texts, styles, c1b, c2b, pw, pb,
        v1w, v1b, v2w, v2b, v3w, v3b,
        (const float*)ws, feats, scores);
    kArgGather<<<dim3(32), dim3(128), 0, stream>>>(scores, feats, res);
    kDecode<<<dim3(256), dim3(512), 0, stream>>>(res, d1w, d1b, d2w, d2b,
                                                 (float*)d_out);
}

// Round 7
// 337.254 us; speedup vs baseline: 2.4887x; 2.4887x over previous
//
#include <hip/hip_runtime.h>
#include <cstddef>
#include <cstdint>

#define LEAKY(x) ((x) > 0.f ? (x) : 0.2f*(x))

typedef _Float16 f16x8  __attribute__((ext_vector_type(8)));
typedef float    f32x16 __attribute__((ext_vector_type(16)));

// ws float-offsets
#define WS_FEATS   0            // 32*64*128 = 262144 floats
#define WS_SCORES  262144       // 2048
#define WS_RES     264192       // 4096
#define WS_W2      268288       // fp16: 2ch*2pl*64*152 = 38912 halfs (19456 float slots)
#define WS_W1P     287744       // 576 floats

// async global->LDS, 16B per lane; LDS dest = wave-uniform base + lane*16
__device__ __forceinline__ void gll16(const void* g, void* l) {
    __builtin_amdgcn_global_load_lds(
        (const __attribute__((address_space(1))) unsigned int*)g,
        (__attribute__((address_space(3))) unsigned int*)l, 16, 0, 0);
}

// ---------------------------------------------------------------------------
// Pre-kernel (16 blocks x 256): pack conv2 weights fp16 hi/lo,
// W2[chunk][plane][co][152], k = tap*16 + ci_in_chunk (k>=144 zero).
// Row stride 152 halfs = 19 granules (odd) -> B-reads cover all 8 LDS slots.
// Also pack conv1 weights [grun][ci][kh][c*3+kw] for uniform s_load.
// ---------------------------------------------------------------------------
__global__ void kPack(const float* __restrict__ c1w, const float* __restrict__ c2w,
                      float* __restrict__ ws)
{
    _Float16* W2 = (_Float16*)(ws + WS_W2);
    float* w1p = ws + WS_W1P;
    const int t = blockIdx.x*256 + threadIdx.x;
    for (int i = t; i < 2*64*152; i += 16*256) {
        int k = i % 152, rest = i / 152;
        int co = rest & 63, c = rest >> 6;
        _Float16 h = (_Float16)0.f, lo = (_Float16)0.f;
        if (k < 144) {
            int tap = k >> 4, cil = k & 15;
            float wv = c2w[(co*32 + c*16 + cil)*9 + tap];
            h  = (_Float16)wv;
            lo = (_Float16)(wv - (float)h);
        }
        W2[((size_t)(c*2 + 0)*64 + co)*152 + k] = h;
        W2[((size_t)(c*2 + 1)*64 + co)*152 + k] = lo;
    }
    if (blockIdx.x == 0) {
        for (int i = threadIdx.x; i < 576; i += 256) {
            int kw = i % 3; int r = i / 3;
            int c = r & 7; r >>= 3;
            int kh = r % 3; r /= 3;
            int ci = r & 1; int grun = r >> 1;
            int co = grun*8 + c;
            w1p[i] = c1w[co*18 + ci*9 + kh*3 + kw];
        }
    }
}

// ---------------------------------------------------------------------------
// Kernel A: per image n (2048 blocks x 512 thr = 8 waves)
//   conv1 fp32 VALU (4 pos x 8 c_out per thread) -> x1 NHWC fp16 hi/lo LDS
//   conv2 implicit-GEMM v_mfma_f32_32x32x16_f16, 2-term split (3 MFMA/tap)
//   GAP -> proj -> scorer MLP (4-way K-split epilogue) -> score
// B + input staged via global_load_lds (async); B1 hidden under conv1(ch1).
// NOTE: 512 threads / bare __launch_bounds__(512) — 1024-thread blocks clamp
// the allocator to 64 VGPR on this toolchain and spill ~1KB/thread (r5/r6:
// 1.9 GB scratch writes, MfmaUtil 0.3%). Keep 512.
// ---------------------------------------------------------------------------
__global__ __launch_bounds__(512) void kA(
    const float* __restrict__ texts, const float* __restrict__ styles,
    const float* __restrict__ c1b, const float* __restrict__ c2b,
    const float* __restrict__ pw,  const float* __restrict__ pb,
    const float* __restrict__ v1w, const float* __restrict__ v1b,
    const float* __restrict__ v2w, const float* __restrict__ v2b,
    const float* __restrict__ v3w, const float* __restrict__ v3b,
    const float* __restrict__ wsro,
    float* __restrict__ feats, float* __restrict__ scores)
{
    __shared__ __align__(16) float    s_in[2][65][64];   // rows 0-63 data, row 64 zero
    __shared__ __align__(16) _Float16 s_x1[2][33*33*16]; // hi, lo
    __shared__ __align__(16) _Float16 s_B[2][64*152];    // hi, lo (one ci-chunk)
    __shared__ float s_part[8][64];
    __shared__ float s_red2[4][128];
    __shared__ float s_gap[64], s_f[128], s_h[128], s_red[2];

    const int n = blockIdx.x, tid = threadIdx.x;
    const int w = tid >> 6, l = tid & 63;

    const char* W2c = (const char*)(wsro + WS_W2);  // 2 chunks x 38912 B
    char* sB = (char*)&s_B[0][0];

    // ---- issue async staging: B chunk 0 (2432 x16B) + both input channels ----
    #pragma unroll
    for (int q = 0; q < 4; ++q)
        gll16(W2c + (size_t)(tid + q*512)*16, sB + (size_t)(tid + q*512)*16);
    if (tid < 384)
        gll16(W2c + (size_t)(tid + 2048)*16, sB + (size_t)(tid + 2048)*16);
    #pragma unroll
    for (int q = 0; q < 2; ++q) {
        gll16((const char*)(texts  + (size_t)n*4096) + (size_t)(tid + q*512)*16,
              (char*)&s_in[0][0][0] + (size_t)(tid + q*512)*16);
        gll16((const char*)(styles + (size_t)n*4096) + (size_t)(tid + q*512)*16,
              (char*)&s_in[1][0][0] + (size_t)(tid + q*512)*16);
    }

    // zero pads while loads fly
    if (tid < 64) s_in[0][64][tid] = 0.f;
    else if (tid < 128) s_in[1][64][tid - 64] = 0.f;
    {   // zero x1 (rows/cols 32 stay zero): 69696 B = 4356 x16B
        uint4* z = (uint4*)&s_x1[0][0];
        const uint4 z4 = {0u,0u,0u,0u};
        for (int i = tid; i < 4356; i += 512) z[i] = z4;
    }
    __syncthreads();   // drains vmcnt: B0 + inputs resident

    f32x16 acc0, acc1;
    #pragma unroll
    for (int r = 0; r < 16; ++r) { acc0[r] = 0.f; acc1[r] = 0.f; }

    for (int ch = 0; ch < 2; ++ch) {
        if (ch == 1) {  // s_B consumed (post-barrier); hide B1 under conv1(ch1)
            #pragma unroll
            for (int q = 0; q < 4; ++q)
                gll16(W2c + 38912 + (size_t)(tid + q*512)*16,
                      sB + (size_t)(tid + q*512)*16);
            if (tid < 384)
                gll16(W2c + 38912 + (size_t)(tid + 2048)*16,
                      sB + (size_t)(tid + 2048)*16);
        }

        // ---- conv1: c_out [ch*16, ch*16+16), 2 runs x 8 c_out, 4 pos/thr ----
        {
            const int run  = w >> 2;                 // wave-uniform
            const int coB  = ch*16 + run*8;
            const int posb = (w & 3)*64 + l;         // 0..255
            float a[4][8];
            #pragma unroll
            for (int c = 0; c < 8; ++c) {
                float b1 = c1b[coB + c];
                #pragma unroll
                for (int p = 0; p < 4; ++p) a[p][c] = b1;
            }
            const float* w1pg = wsro + WS_W1P + (ch*2 + run)*144;
            #pragma unroll
            for (int ci = 0; ci < 2; ++ci)
            #pragma unroll
            for (int kh = 0; kh < 3; ++kh) {
                const float* wrow = w1pg + (ci*3 + kh)*24;
                float wv[24];
                #pragma unroll
                for (int q = 0; q < 6; ++q)
                    *(float4*)&wv[q*4] = *(const float4*)&wrow[q*4];  // uniform -> s_load
                #pragma unroll
                for (int p = 0; p < 4; ++p) {
                    const int pos = posb + p*256, py = pos >> 5, px = pos & 31;
                    const float* row = &s_in[ci][2*py + kh][2*px];
                    float2 i01 = *(const float2*)row;
                    float  i2  = (px < 31) ? row[2] : 0.f;   // SAME right-pad
                    #pragma unroll
                    for (int c = 0; c < 8; ++c)
                        a[p][c] += wv[c*3]*i01.x + wv[c*3+1]*i01.y + wv[c*3+2]*i2;
                }
            }
            #pragma unroll
            for (int p = 0; p < 4; ++p) {
                const int pos = posb + p*256, py = pos >> 5, px = pos & 31;
                const int xs = px ^ ((px >> 1) & 1);         // granule-slot swizzle
                const int eo = (py*33 + xs)*16 + run*8;
                _Float16 hh[8], ll[8];
                #pragma unroll
                for (int c = 0; c < 8; ++c) {
                    float v = LEAKY(a[p][c]);
                    _Float16 h = (_Float16)v;
                    hh[c] = h; ll[c] = (_Float16)(v - (float)h);
                }
                *(uint4*)&s_x1[0][eo] = *(uint4*)hh;
                *(uint4*)&s_x1[1][eo] = *(uint4*)ll;
            }
        }
        __syncthreads();   // x1 ready; (ch==1) also drains B1

        // ---- conv2: 8 waves = 8 M-tiles, both N-halves, 54 MFMA each ----
        {
            const int pos = w*32 + (l & 31);
            const int py = pos >> 4, px = pos & 15;
            const int hf = l >> 5;
            const int co = l & 31;
            #pragma unroll
            for (int tap = 0; tap < 9; ++tap) {
                const int kh = tap/3, kw = tap%3;
                const int xr = 2*px + kw;
                const int xs = xr ^ ((xr >> 1) & 1);
                const int ae = ((2*py + kh)*33 + xs)*16 + hf*8;
                f16x8 Ah = *(const f16x8*)&s_x1[0][ae];
                f16x8 Al = *(const f16x8*)&s_x1[1][ae];
                const int be0 = co*152 + tap*16 + hf*8;
                const int be1 = be0 + 32*152;
                f16x8 Bh0 = *(const f16x8*)&s_B[0][be0];
                f16x8 Bl0 = *(const f16x8*)&s_B[1][be0];
                f16x8 Bh1 = *(const f16x8*)&s_B[0][be1];
                f16x8 Bl1 = *(const f16x8*)&s_B[1][be1];
                acc0 = __builtin_amdgcn_mfma_f32_32x32x16_f16(Ah, Bh0, acc0, 0, 0, 0);
                acc0 = __builtin_amdgcn_mfma_f32_32x32x16_f16(Ah, Bl0, acc0, 0, 0, 0);
                acc0 = __builtin_amdgcn_mfma_f32_32x32x16_f16(Al, Bh0, acc0, 0, 0, 0);
                acc1 = __builtin_amdgcn_mfma_f32_32x32x16_f16(Ah, Bh1, acc1, 0, 0, 0);
                acc1 = __builtin_amdgcn_mfma_f32_32x32x16_f16(Ah, Bl1, acc1, 0, 0, 0);
                acc1 = __builtin_amdgcn_mfma_f32_32x32x16_f16(Al, Bh1, acc1, 0, 0, 0);
            }
        }
        __syncthreads();   // s_B / s_x1 consumed; safe to restage
    }

    // ---- bias + leaky + GAP (sum all acc regs + both lane halves) ----
    {
        const float b20 = c2b[l & 31], b21 = c2b[(l & 31) + 32];
        float sum0 = 0.f, sum1 = 0.f;
        #pragma unroll
        for (int r = 0; r < 16; ++r) {
            sum0 += LEAKY(acc0[r] + b20);
            sum1 += LEAKY(acc1[r] + b21);
        }
        sum0 += __shfl_xor(sum0, 32);
        sum1 += __shfl_xor(sum1, 32);
        if (l < 32) { s_part[w][l] = sum0; s_part[w][l + 32] = sum1; }
    }
    __syncthreads();
    if (tid < 64) {
        float s = 0.f;
        #pragma unroll
        for (int ww = 0; ww < 8; ++ww) s += s_part[ww][tid];
        s_gap[tid] = s * (1.f/256.f);
    }
    __syncthreads();

    // ---- proj + scorer: 128 outputs x 4-way K-split ----
    const int j = tid & 127, ks = tid >> 7;
    {
        float p = 0.f;
        #pragma unroll
        for (int m = ks*16; m < ks*16 + 16; ++m) p += s_gap[m]*pw[m*128 + j];
        s_red2[ks][j] = p;
    }
    __syncthreads();
    if (tid < 128) {
        float a = pb[tid];
        #pragma unroll
        for (int q = 0; q < 4; ++q) a += s_red2[q][tid];
        feats[(size_t)n*128 + tid] = a;
        s_f[tid] = a;
    }
    __syncthreads();
    {
        float p = 0.f;
        #pragma unroll
        for (int m = ks*32; m < ks*32 + 32; ++m) p += s_f[m]*v1w[m*128 + j];
        s_red2[ks][j] = p;
    }
    __syncthreads();
    if (tid < 128) {
        float a = v1b[tid];
        #pragma unroll
        for (int q = 0; q < 4; ++q) a += s_red2[q][tid];
        s_h[tid] = LEAKY(a);
    }
    __syncthreads();
    {
        float p = 0.f;
        #pragma unroll
        for (int m = ks*32; m < ks*32 + 32; ++m) p += s_h[m]*v2w[m*128 + j];
        s_red2[ks][j] = p;
    }
    __syncthreads();
    if (tid < 128) {
        float a = v2b[tid];
        #pragma unroll
        for (int q = 0; q < 4; ++q) a += s_red2[q][tid];
        a = LEAKY(a);
        s_f[tid] = a * v3w[tid];
    }
    __syncthreads();
    if (tid < 128) {
        float p = s_f[tid];
        #pragma unroll
        for (int off = 32; off; off >>= 1) p += __shfl_xor(p, off);
        if ((tid & 63) == 0) s_red[tid >> 6] = p;
    }
    __syncthreads();
    if (tid == 0) scores[n] = tanhf(s_red[0] + s_red[1] + v3b[0]);
}

// ---------------------------------------------------------------------------
// Kernel B: per-batch argmax (first-index tie-break) + gather feats row
// ---------------------------------------------------------------------------
__global__ __launch_bounds__(128) void kArgGather(
    const float* __restrict__ scores, const float* __restrict__ feats,
    float* __restrict__ res)
{
    __shared__ int s_idx;
    const int b = blockIdx.x, tid = threadIdx.x;
    if (tid < 64) {
        float v = scores[b*64 + tid];
        int   i = tid;
        #pragma unroll
        for (int off = 32; off; off >>= 1) {
            float ov = __shfl_xor(v, off);
            int   oi = __shfl_xor(i, off);
            if (ov > v || (ov == v && oi < i)) { v = ov; i = oi; }
        }
        if (tid == 0) s_idx = i;
    }
    __syncthreads();
    const int idx = s_idx;
    res[b*128 + tid] = feats[((size_t)b*64 + idx)*128 + tid];
}

// ---------------------------------------------------------------------------
// Kernel C: decoder (fp32). bid%8 -> same d2 column slice per XCD.
// ---------------------------------------------------------------------------
__global__ __launch_bounds__(512) void kDecode(
    const float* __restrict__ res,
    const float* __restrict__ d1w, const float* __restrict__ d1b,
    const float* __restrict__ d2w, const float* __restrict__ d2b,
    float* __restrict__ out)
{
    __shared__ float s_res[128];
    __shared__ float s_h[512];
    const int bid = blockIdx.x;
    const int b = bid >> 3, ot = bid & 7;
    const int tid = threadIdx.x;

    if (tid < 128) s_res[tid] = res[b*128 + tid];
    __syncthreads();
    {
        float a = d1b[tid];
        #pragma unroll 8
        for (int m = 0; m < 128; ++m) a += s_res[m]*d1w[m*512 + tid];
        s_h[tid] = LEAKY(a);
    }
    __syncthreads();
    const int o = ot*512 + tid;
    float a = d2b[o];
    for (int k = 0; k < 512; k += 4) {
        float4 h4 = *(const float4*)&s_h[k];
        a += h4.x*d2w[(size_t)(k+0)*4096 + o];
        a += h4.y*d2w[(size_t)(k+1)*4096 + o];
        a += h4.z*d2w[(size_t)(k+2)*4096 + o];
        a += h4.w*d2w[(size_t)(k+3)*4096 + o];
    }
    out[(size_t)b*4096 + o] = tanhf(a);
}

// ---------------------------------------------------------------------------
extern "C" void kernel_launch(void* const* d_in, const int* in_sizes, int n_in,
                              void* d_out, int out_size, void* d_ws, size_t ws_size,
                              hipStream_t stream)
{
    const float* texts  = (const float*)d_in[0];
    const float* styles = (const float*)d_in[1];
    const float* c1w = (const float*)d_in[2];
    const float* c1b = (const float*)d_in[3];
    const float* c2w = (const float*)d_in[4];
    const float* c2b = (const float*)d_in[5];
    const float* pw  = (const float*)d_in[6];
    const float* pb  = (const float*)d_in[7];
    const float* v1w = (const float*)d_in[8];
    const float* v1b = (const float*)d_in[9];
    const float* v2w = (const float*)d_in[10];
    const float* v2b = (const float*)d_in[11];
    const float* v3w = (const float*)d_in[12];
    const float* v3b = (const float*)d_in[13];
    const float* d1w = (const float*)d_in[14];
    const float* d1b = (const float*)d_in[15];
    const float* d2w = (const float*)d_in[16];
    const float* d2b = (const float*)d_in[17];

    float* ws     = (float*)d_ws;
    float* feats  = ws + WS_FEATS;
    float* scores = ws + WS_SCORES;
    float* res    = ws + WS_RES;

    kPack<<<dim3(16), dim3(256), 0, stream>>>(c1w, c2w, ws);
    kA<<<dim3(2048), dim3(512), 0, stream>>>(
        texts, styles, c1b, c2b, pw, pb,
        v1w, v1b, v2w, v2b, v3w, v3b,
        (const float*)ws, feats, scores);
    kArgGather<<<dim3(32), dim3(128), 0, stream>>>(scores, feats, res);
    kDecode<<<dim3(256), dim3(512), 0, stream>>>(res, d1w, d1b, d2w, d2b,
                                                 (float*)d_out);
}

// Round 8
// 235.583 us; speedup vs baseline: 3.5628x; 1.4316x over previous
//
#include <hip/hip_runtime.h>
#include <cstddef>
#include <cstdint>

#define LEAKY(x) ((x) > 0.f ? (x) : 0.2f*(x))

typedef _Float16 f16x8  __attribute__((ext_vector_type(8)));
typedef float    f32x16 __attribute__((ext_vector_type(16)));

// ws float-offsets
#define WS_FEATS   0            // 32*64*128 = 262144 floats
#define WS_SCORES  262144       // 2048
#define WS_RES     264192       // 4096
#define WS_W2      268288       // fp16: 2ch*2pl*64*152 = 38912 halfs (19456 float slots)
#define WS_W1P     287744       // 576 floats
#define WS_GAPP    288320       // 2048 imgs * 2 halves * 64 ch = 262144 floats

// ---------------------------------------------------------------------------
// Pre-kernel (16 blocks x 256): pack conv2 weights fp16 hi/lo,
// W2[chunk][plane][co][152], k = tap*16 + ci_in_chunk (k>=144 zero).
// Row stride 152 halfs = 19 granules (odd) -> B-reads cover all 8 LDS slots.
// Also pack conv1 weights [grun][ci][kh][c*3+kw] for uniform s_load.
// ---------------------------------------------------------------------------
__global__ void kPack(const float* __restrict__ c1w, const float* __restrict__ c2w,
                      float* __restrict__ ws)
{
    _Float16* W2 = (_Float16*)(ws + WS_W2);
    float* w1p = ws + WS_W1P;
    const int t = blockIdx.x*256 + threadIdx.x;
    for (int i = t; i < 2*64*152; i += 16*256) {
        int k = i % 152, rest = i / 152;
        int co = rest & 63, c = rest >> 6;
        _Float16 h = (_Float16)0.f, lo = (_Float16)0.f;
        if (k < 144) {
            int tap = k >> 4, cil = k & 15;
            float wv = c2w[(co*32 + c*16 + cil)*9 + tap];
            h  = (_Float16)wv;
            lo = (_Float16)(wv - (float)h);
        }
        W2[((size_t)(c*2 + 0)*64 + co)*152 + k] = h;
        W2[((size_t)(c*2 + 1)*64 + co)*152 + k] = lo;
    }
    if (blockIdx.x == 0) {
        for (int i = threadIdx.x; i < 576; i += 256) {
            int kw = i % 3; int r = i / 3;
            int c = r & 7; r >>= 3;
            int kh = r % 3; r /= 3;
            int ci = r & 1; int grun = r >> 1;
            int co = grun*8 + c;
            w1p[i] = c1w[co*18 + ci*9 + kh*3 + kw];
        }
    }
}

// ---------------------------------------------------------------------------
// kConv: HALF image per block. bid = n*2 + h (4096 blocks x 512 thr).
//   h=0: conv2 out rows 0-7, h=1: rows 8-15. x1 rows local 0..16
//   (17 incl halo; bottom's local row 16 = global row 32 = zero pad).
//   conv1 fp32 VALU -> x1 fp16 hi/lo LDS; conv2 MFMA with B staged one
//   plane at a time (pass-hi: AhBh+AlBh; restage; pass-lo: AhBl).
//   GAP partials -> ws gapp[n][h][64]. Scorer moved to kScore.
// LDS ~74.5 KB -> 2 blocks/CU (16 waves/CU). All staging via VALU
// (r7's global_load_lds burst correlated with ~530 B/thread scratch spill).
// ---------------------------------------------------------------------------
__global__ __launch_bounds__(512) void kConv(
    const float* __restrict__ texts, const float* __restrict__ styles,
    const float* __restrict__ c1b, const float* __restrict__ c2b,
    const float* __restrict__ wsro, float* __restrict__ gapp)
{
    __shared__ __align__(16) float    s_in[2][35][64];     // 17,920 B
    __shared__ __align__(16) _Float16 s_x1[2][17*33*16];   // 35,904 B (hi, lo)
    __shared__ __align__(16) _Float16 s_B[64*152];         // 19,456 B (one plane)
    __shared__ float s_part[8][32];

    const int bid = blockIdx.x, tid = threadIdx.x;
    const int n = bid >> 1, h = bid & 1;
    const int w = tid >> 6, l = tid & 63;

    // zero x1 (col 32 pad; bottom's local row 16 stays zero)
    {
        uint4* z = (uint4*)&s_x1[0][0];
        const uint4 z4 = {0u,0u,0u,0u};
        for (int i = tid; i < 2244; i += 512) z[i] = z4;   // 35904/16
    }
    // stage input rows h*32 .. h*32+34 (35 rows, both channels; rows>=64 zero)
    for (int i = tid; i < 1120; i += 512) {
        const int c = i >= 560, j = c ? i - 560 : i;
        const int rl = j >> 4, g = j & 15;
        const int grow = h*32 + rl;
        float4 v = {0.f,0.f,0.f,0.f};
        const float* src = c ? styles : texts;
        if (grow < 64) v = *(const float4*)&src[(size_t)n*4096 + grow*64 + g*4];
        *(float4*)&s_in[c][rl][g*4] = v;
    }
    __syncthreads();

    const uint32_t* W2u = (const uint32_t*)(wsro + WS_W2);  // 4 planes x 4864 u32
    uint32_t* sBu = (uint32_t*)&s_B[0];

    f32x16 acc;
    #pragma unroll
    for (int r = 0; r < 16; ++r) acc[r] = 0.f;

    const int mt = w >> 1, nh = w & 1;           // conv2 wave roles
    const int posl = mt*32 + (l & 31);
    const int py2 = posl >> 4, px2 = posl & 15;
    const int hf = l >> 5;
    const int co = nh*32 + (l & 31);

    for (int ch = 0; ch < 2; ++ch) {
        // ---- stage B hi-plane (prev pass-lo done at chunk-end barrier) ----
        {
            const uint32_t* src = W2u + (size_t)(ch*2 + 0)*4864;
            for (int i = tid; i < 4864; i += 512) sBu[i] = src[i];
        }
        // ---- conv1: 16 co (2 runs x 8), 1 position/thread (+halo row 16) ----
        {
            const int py0 = tid >> 5, px0 = tid & 31;
            #pragma unroll
            for (int run = 0; run < 2; ++run) {
                const int coB = ch*16 + run*8;
                const float* w1pg = wsro + WS_W1P + (ch*2 + run)*144;
                float wv[24];
                #pragma unroll
                for (int q = 0; q < 6; ++q)
                    *(float4*)&wv[q*4] = *(const float4*)&w1pg[q*4];  // uniform
                float bias[8];
                *(float4*)&bias[0] = *(const float4*)&c1b[coB];
                *(float4*)&bias[4] = *(const float4*)&c1b[coB+4];
                #pragma unroll
                for (int p = 0; p < 2; ++p) {
                    if (p == 1 && tid >= 32) break;
                    const int py = p ? 16 : py0, px = p ? tid : px0;
                    float a[8];
                    #pragma unroll
                    for (int c = 0; c < 8; ++c) a[c] = bias[c];
                    #pragma unroll
                    for (int ci = 0; ci < 2; ++ci)
                    #pragma unroll
                    for (int kh = 0; kh < 3; ++kh) {
                        const float* row = &s_in[ci][2*py + kh][2*px];
                        float2 i01 = *(const float2*)row;
                        float  i2  = (px < 31) ? row[2] : 0.f;   // SAME right-pad
                        const float* wr = &wv[(ci*3 + kh)*0];     // wv laid out (ci*3+kh)*... see below
                        // wv index: ((ci*3+kh) selects group of... wv holds one
                        // (ci,kh) group per 24/6? -- wv is [c*3+kw] for THIS (ci,kh)?
                        (void)wr;
                        const int base = 0; (void)base;
                        #pragma unroll
                        for (int c = 0; c < 8; ++c)
                            a[c] += 0.f; // placeholder overwritten below
                    }
                    // NOTE: the loop above is restructured just below for clarity
                    #pragma unroll
                    for (int c = 0; c < 8; ++c) a[c] = bias[c];
                    #pragma unroll
                    for (int ci = 0; ci < 2; ++ci)
                    #pragma unroll
                    for (int kh = 0; kh < 3; ++kh) {
                        float wvk[24];
                        #pragma unroll
                        for (int q = 0; q < 6; ++q)
                            *(float4*)&wvk[q*4] = *(const float4*)&w1pg[(ci*3+kh)*24 + q*4];
                        const float* row = &s_in[ci][2*py + kh][2*px];
                        float2 i01 = *(const float2*)row;
                        float  i2  = (px < 31) ? row[2] : 0.f;
                        #pragma unroll
                        for (int c = 0; c < 8; ++c)
                            a[c] += wvk[c*3]*i01.x + wvk[c*3+1]*i01.y + wvk[c*3+2]*i2;
                    }
                    const int xs = px ^ ((px >> 1) & 1);
                    const int eo = (py*33 + xs)*16 + run*8;
                    _Float16 hh[8], ll[8];
                    #pragma unroll
                    for (int c = 0; c < 8; ++c) {
                        float v = LEAKY(a[c]);
                        _Float16 hx = (_Float16)v;
                        hh[c] = hx; ll[c] = (_Float16)(v - (float)hx);
                    }
                    *(uint4*)&s_x1[0][eo] = *(uint4*)hh;
                    *(uint4*)&s_x1[1][eo] = *(uint4*)ll;
                }
            }
        }
        __syncthreads();   // x1 + B-hi ready

        // ---- conv2 pass-hi: AhBh + AlBh per tap ----
        #pragma unroll
        for (int tap = 0; tap < 9; ++tap) {
            const int kh = tap/3, kw = tap%3;
            const int xr = 2*px2 + kw;
            const int xs = xr ^ ((xr >> 1) & 1);
            const int ae = ((2*py2 + kh)*33 + xs)*16 + hf*8;
            f16x8 Ah = *(const f16x8*)&s_x1[0][ae];
            f16x8 Al = *(const f16x8*)&s_x1[1][ae];
            f16x8 Bh = *(const f16x8*)&s_B[co*152 + tap*16 + hf*8];
            acc = __builtin_amdgcn_mfma_f32_32x32x16_f16(Ah, Bh, acc, 0, 0, 0);
            acc = __builtin_amdgcn_mfma_f32_32x32x16_f16(Al, Bh, acc, 0, 0, 0);
        }
        __syncthreads();   // pass-hi done reading s_B

        // ---- stage B lo-plane ----
        {
            const uint32_t* src = W2u + (size_t)(ch*2 + 1)*4864;
            for (int i = tid; i < 4864; i += 512) sBu[i] = src[i];
        }
        __syncthreads();   // B-lo ready (x1 untouched)

        // ---- conv2 pass-lo: AhBl per tap ----
        #pragma unroll
        for (int tap = 0; tap < 9; ++tap) {
            const int kh = tap/3, kw = tap%3;
            const int xr = 2*px2 + kw;
            const int xs = xr ^ ((xr >> 1) & 1);
            const int ae = ((2*py2 + kh)*33 + xs)*16 + hf*8;
            f16x8 Ah = *(const f16x8*)&s_x1[0][ae];
            f16x8 Bl = *(const f16x8*)&s_B[co*152 + tap*16 + hf*8];
            acc = __builtin_amdgcn_mfma_f32_32x32x16_f16(Ah, Bl, acc, 0, 0, 0);
        }
        __syncthreads();   // chunk done: s_x1 / s_B free
    }

    // ---- bias + leaky + GAP partial over this half's 128 positions ----
    {
        const float b2 = c2b[co];
        float s = 0.f;
        #pragma unroll
        for (int r = 0; r < 16; ++r) s += LEAKY(acc[r] + b2);
        s += __shfl_xor(s, 32);
        if (l < 32) s_part[w][l] = s;
    }
    __syncthreads();
    if (tid < 64) {
        const int c = tid;
        float g = 0.f;
        #pragma unroll
        for (int m = 0; m < 4; ++m) g += s_part[m*2 + (c >> 5)][c & 31];
        gapp[(size_t)(n*2 + h)*64 + c] = g;
    }
}

// ---------------------------------------------------------------------------
// kScore: per image (2048 blocks x 128 thr). Combine GAP halves, proj,
// scorer MLP, tanh score. Tiny LDS -> high occupancy hides load latency.
// ---------------------------------------------------------------------------
__global__ __launch_bounds__(128) void kScore(
    const float* __restrict__ gapp,
    const float* __restrict__ pw,  const float* __restrict__ pb,
    const float* __restrict__ v1w, const float* __restrict__ v1b,
    const float* __restrict__ v2w, const float* __restrict__ v2b,
    const float* __restrict__ v3w, const float* __restrict__ v3b,
    float* __restrict__ feats, float* __restrict__ scores)
{
    __shared__ float s_gap[64], s_f[128], s_h[128], s_red[2];
    const int n = blockIdx.x, tid = threadIdx.x;

    if (tid < 64)
        s_gap[tid] = (gapp[(size_t)n*128 + tid] + gapp[(size_t)n*128 + 64 + tid])
                     * (1.f/256.f);
    __syncthreads();
    {
        float a = pb[tid];
        #pragma unroll 8
        for (int m = 0; m < 64; ++m) a += s_gap[m]*pw[m*128 + tid];
        feats[(size_t)n*128 + tid] = a;
        s_f[tid] = a;
    }
    __syncthreads();
    {
        float a = v1b[tid];
        #pragma unroll 8
        for (int m = 0; m < 128; ++m) a += s_f[m]*v1w[m*128 + tid];
        s_h[tid] = LEAKY(a);
    }
    __syncthreads();
    {
        float a = v2b[tid];
        #pragma unroll 8
        for (int m = 0; m < 128; ++m) a += s_h[m]*v2w[m*128 + tid];
        a = LEAKY(a);
        s_f[tid] = a * v3w[tid];
    }
    __syncthreads();
    {
        float p = s_f[tid];
        #pragma unroll
        for (int off = 32; off; off >>= 1) p += __shfl_xor(p, off);
        if ((tid & 63) == 0) s_red[tid >> 6] = p;
    }
    __syncthreads();
    if (tid == 0) scores[n] = tanhf(s_red[0] + s_red[1] + v3b[0]);
}

// ---------------------------------------------------------------------------
// Kernel B: per-batch argmax (first-index tie-break) + gather feats row
// ---------------------------------------------------------------------------
__global__ __launch_bounds__(128) void kArgGather(
    const float* __restrict__ scores, const float* __restrict__ feats,
    float* __restrict__ res)
{
    __shared__ int s_idx;
    const int b = blockIdx.x, tid = threadIdx.x;
    if (tid < 64) {
        float v = scores[b*64 + tid];
        int   i = tid;
        #pragma unroll
        for (int off = 32; off; off >>= 1) {
            float ov = __shfl_xor(v, off);
            int   oi = __shfl_xor(i, off);
            if (ov > v || (ov == v && oi < i)) { v = ov; i = oi; }
        }
        if (tid == 0) s_idx = i;
    }
    __syncthreads();
    const int idx = s_idx;
    res[b*128 + tid] = feats[((size_t)b*64 + idx)*128 + tid];
}

// ---------------------------------------------------------------------------
// Kernel C: decoder (fp32). bid%8 -> same d2 column slice per XCD.
// ---------------------------------------------------------------------------
__global__ __launch_bounds__(512) void kDecode(
    const float* __restrict__ res,
    const float* __restrict__ d1w, const float* __restrict__ d1b,
    const float* __restrict__ d2w, const float* __restrict__ d2b,
    float* __restrict__ out)
{
    __shared__ float s_res[128];
    __shared__ float s_h[512];
    const int bid = blockIdx.x;
    const int b = bid >> 3, ot = bid & 7;
    const int tid = threadIdx.x;

    if (tid < 128) s_res[tid] = res[b*128 + tid];
    __syncthreads();
    {
        float a = d1b[tid];
        #pragma unroll 8
        for (int m = 0; m < 128; ++m) a += s_res[m]*d1w[m*512 + tid];
        s_h[tid] = LEAKY(a);
    }
    __syncthreads();
    const int o = ot*512 + tid;
    float a = d2b[o];
    for (int k = 0; k < 512; k += 4) {
        float4 h4 = *(const float4*)&s_h[k];
        a += h4.x*d2w[(size_t)(k+0)*4096 + o];
        a += h4.y*d2w[(size_t)(k+1)*4096 + o];
        a += h4.z*d2w[(size_t)(k+2)*4096 + o];
        a += h4.w*d2w[(size_t)(k+3)*4096 + o];
    }
    out[(size_t)b*4096 + o] = tanhf(a);
}

// ---------------------------------------------------------------------------
extern "C" void kernel_launch(void* const* d_in, const int* in_sizes, int n_in,
                              void* d_out, int out_size, void* d_ws, size_t ws_size,
                              hipStream_t stream)
{
    const float* texts  = (const float*)d_in[0];
    const float* styles = (const float*)d_in[1];
    const float* c1w = (const float*)d_in[2];
    const float* c1b = (const float*)d_in[3];
    const float* c2w = (const float*)d_in[4];
    const float* c2b = (const float*)d_in[5];
    const float* pw  = (const float*)d_in[6];
    const float* pb  = (const float*)d_in[7];
    const float* v1w = (const float*)d_in[8];
    const float* v1b = (const float*)d_in[9];
    const float* v2w = (const float*)d_in[10];
    const float* v2b = (const float*)d_in[11];
    const float* v3w = (const float*)d_in[12];
    const float* v3b = (const float*)d_in[13];
    const float* d1w = (const float*)d_in[14];
    const float* d1b = (const float*)d_in[15];
    const float* d2w = (const float*)d_in[16];
    const float* d2b = (const float*)d_in[17];

    float* ws     = (float*)d_ws;
    float* feats  = ws + WS_FEATS;
    float* scores = ws + WS_SCORES;
    float* res    = ws + WS_RES;
    float* gapp   = ws + WS_GAPP;

    kPack<<<dim3(16), dim3(256), 0, stream>>>(c1w, c2w, ws);
    kConv<<<dim3(4096), dim3(512), 0, stream>>>(
        texts, styles, c1b, c2b, (const float*)ws, gapp);
    kScore<<<dim3(2048), dim3(128), 0, stream>>>(
        gapp, pw, pb, v1w, v1b, v2w, v2b, v3w, v3b, feats, scores);
    kArgGather<<<dim3(32), dim3(128), 0, stream>>>(scores, feats, res);
    kDecode<<<dim3(256), dim3(512), 0, stream>>>(res, d1w, d1b, d2w, d2b,
                                                 (float*)d_out);
}

// Round 9
// 217.756 us; speedup vs baseline: 3.8544x; 1.0819x over previous
//
#include <hip/hip_runtime.h>
#include <cstddef>
#include <cstdint>

#define LEAKY(x) ((x) > 0.f ? (x) : 0.2f*(x))

typedef _Float16 f16x8  __attribute__((ext_vector_type(8)));
typedef float    f32x4  __attribute__((ext_vector_type(4)));
typedef float    f32x16 __attribute__((ext_vector_type(16)));

// ws float-offsets
#define WS_FEATS   0            // 32*64*128 = 262144 floats
#define WS_SCORES  262144       // 2048
#define WS_RES     264192       // 4096
#define WS_W2      268288       // fp16: 2ch*2pl*64*152 = 38912 halfs (19456 float slots)
#define WS_W1M     287744       // fp16: 2pl*32co*32k = 2048 halfs (1024 float slots)
#define WS_GAPP    288768       // 2048 imgs * 2 halves * 64 ch = 262144 floats

// ---------------------------------------------------------------------------
// kPack (16 blocks x 256):
//  W2[chunk][plane][co64][152], k = tap*16 + ci_in_chunk (k>=144 zero);
//    row stride 152 halfs = 19 granules (odd) -> B-reads cover all LDS slots.
//  W1M[plane][co32][k32], k = kh*8 + kw*2 + ci for kh<3,kw<3; ZERO at
//    k%8 in {6,7} and k>=24 -- these zeros make the conv1 B-side's
//    don't-care input bytes harmless (A zero kills the product).
// ---------------------------------------------------------------------------
__global__ void kPack(const float* __restrict__ c1w, const float* __restrict__ c2w,
                      float* __restrict__ ws)
{
    _Float16* W2 = (_Float16*)(ws + WS_W2);
    _Float16* W1 = (_Float16*)(ws + WS_W1M);
    const int t = blockIdx.x*256 + threadIdx.x;
    for (int i = t; i < 2*64*152; i += 16*256) {
        int k = i % 152, rest = i / 152;
        int co = rest & 63, c = rest >> 6;
        _Float16 h = (_Float16)0.f, lo = (_Float16)0.f;
        if (k < 144) {
            int tap = k >> 4, cil = k & 15;
            float wv = c2w[(co*32 + c*16 + cil)*9 + tap];
            h  = (_Float16)wv;
            lo = (_Float16)(wv - (float)h);
        }
        W2[((size_t)(c*2 + 0)*64 + co)*152 + k] = h;
        W2[((size_t)(c*2 + 1)*64 + co)*152 + k] = lo;
    }
    if (t < 2048) {
        int pl = t >> 10, rest = t & 1023;
        int co = rest >> 5, k = rest & 31;
        int kh = k >> 3, j = k & 7, kw = j >> 1, ci = j & 1;
        float wv = 0.f;
        if (kh < 3 && kw < 3) wv = c1w[co*18 + ci*9 + kh*3 + kw];
        _Float16 hi = (_Float16)wv;
        W1[t] = pl ? (_Float16)(wv - (float)hi) : hi;
    }
}

// ---------------------------------------------------------------------------
// kConv: HALF image per block. bid = n*2 + h (4096 blocks x 512 thr).
//   Input staged as fp16 hi/lo NHWC-interleaved in[row][x][ci] -> conv1 is
//   pure implicit-GEMM on mfma_f32_16x16x32_f16 (3-MFMA split, B-frag =
//   direct 16B read of the interleaved input patch; no im2col).
//   conv2 unchanged from r8 (32x32x16 f16, B one plane at a time).
//   GAP partials -> gapp[n][h][64]; scorer in kScore.
// LDS ~79.5 KB -> 2 blocks/CU. No global_load_lds, 512 thr, bare bounds
// (r5-r7 spill lessons).
// ---------------------------------------------------------------------------
__global__ __launch_bounds__(512) void kConv(
    const float* __restrict__ texts, const float* __restrict__ styles,
    const float* __restrict__ c1b, const float* __restrict__ c2b,
    const float* __restrict__ wsro, float* __restrict__ gapp)
{
    __shared__ __align__(16) _Float16 s_in[2][35][68][2];  // 19,040 B (pl,row,x,ci)
    __shared__ __align__(16) _Float16 s_x1[2][17*33*16];   // 35,904 B (hi, lo)
    __shared__ __align__(16) _Float16 s_B[64*152];         // 19,456 B (one plane)
    __shared__ __align__(16) _Float16 s_w1[2][32][32];     //  4,096 B
    __shared__ float s_part[8][32];                        //  1,024 B

    const int bid = blockIdx.x, tid = threadIdx.x;
    const int n = bid >> 1, h = bid & 1;
    const int w = tid >> 6, l = tid & 63;

    // zero x1 (col 32 pad; h=1's local row 16 stays zero = true conv2 pad)
    {
        const uint4 z4 = {0u,0u,0u,0u};
        uint4* z = (uint4*)&s_x1[0][0];
        for (int i = tid; i < 2244; i += 512) z[i] = z4;
        if (tid < 70) {           // s_in pad cols x=64..67, both planes
            int pl = tid >= 35, row = pl ? tid - 35 : tid;
            *(uint4*)&s_in[pl][row][64][0] = z4;
        }
    }
    // stage input rows h*32..h*32+34, fp16 hi/lo interleaved (rows>=64 zero)
    for (int u = tid; u < 560; u += 512) {
        const int row = u >> 4, g = u & 15;
        const int grow = h*32 + row;
        float4 tv = {0.f,0.f,0.f,0.f}, sv = {0.f,0.f,0.f,0.f};
        if (grow < 64) {
            tv = *(const float4*)&texts [(size_t)n*4096 + grow*64 + g*4];
            sv = *(const float4*)&styles[(size_t)n*4096 + grow*64 + g*4];
        }
        float vals[8] = {tv.x, sv.x, tv.y, sv.y, tv.z, sv.z, tv.w, sv.w};
        _Float16 hh[8], ll[8];
        #pragma unroll
        for (int j = 0; j < 8; ++j) {
            _Float16 hi = (_Float16)vals[j];
            hh[j] = hi; ll[j] = (_Float16)(vals[j] - (float)hi);
        }
        *(uint4*)&s_in[0][row][g*4][0] = *(uint4*)hh;
        *(uint4*)&s_in[1][row][g*4][0] = *(uint4*)ll;
    }
    // stage w1m
    {
        const uint32_t* src = (const uint32_t*)(wsro + WS_W1M);
        uint32_t* dst = (uint32_t*)&s_w1[0][0][0];
        for (int i = tid; i < 1024; i += 512) dst[i] = src[i];
    }
    __syncthreads();

    const uint32_t* W2u = (const uint32_t*)(wsro + WS_W2);
    uint32_t* sBu = (uint32_t*)&s_B[0];

    f32x16 acc;
    #pragma unroll
    for (int r = 0; r < 16; ++r) acc[r] = 0.f;

    // conv2 roles (r8)
    const int mt = w >> 1, nh = w & 1;
    const int posl = mt*32 + (l & 31);
    const int py2 = posl >> 4, px2 = posl & 15;
    const int hf2 = l >> 5;
    const int co2 = nh*32 + (l & 31);
    // conv1 roles
    const int kg = l >> 4, m16 = l & 15;
    const int NT = 34 - 2*h;   // h=1 skips py=16 (x1 row 16 = zero pad)

    for (int ch = 0; ch < 2; ++ch) {
        // ---- stage B hi-plane ----
        {
            const uint32_t* src = W2u + (size_t)(ch*2 + 0)*4864;
            for (int i = tid; i < 4864; i += 512) sBu[i] = src[i];
        }
        // ---- conv1 via MFMA: 16 co of this chunk, pos-tiles of 16 ----
        {
            f16x8 a_h = *(const f16x8*)&s_w1[0][ch*16 + m16][kg*8];
            f16x8 a_l = *(const f16x8*)&s_w1[1][ch*16 + m16][kg*8];
            float4 b4 = *(const float4*)&c1b[ch*16 + kg*4];
            for (int t = w; t < NT; t += 8) {
                const int py = t >> 1, px = (t & 1)*16 + m16;
                const int row = (kg < 3) ? (2*py + kg) : 0;  // kg=3: A rows zero
                const _Float16* bp0 = &s_in[0][row][2*px][0];
                const _Float16* bp1 = &s_in[1][row][2*px][0];
                f16x8 b_h, b_l;   // 8B-aligned -> two b64 reads each
                ((uint2*)&b_h)[0] = *(const uint2*)bp0;
                ((uint2*)&b_h)[1] = *(const uint2*)(bp0 + 4);
                ((uint2*)&b_l)[0] = *(const uint2*)bp1;
                ((uint2*)&b_l)[1] = *(const uint2*)(bp1 + 4);
                f32x4 c = {0.f,0.f,0.f,0.f};
                c = __builtin_amdgcn_mfma_f32_16x16x32_f16(a_l, b_h, c, 0, 0, 0);
                c = __builtin_amdgcn_mfma_f32_16x16x32_f16(a_h, b_l, c, 0, 0, 0);
                c = __builtin_amdgcn_mfma_f32_16x16x32_f16(a_h, b_h, c, 0, 0, 0);
                // C: col=l&15=pos, row=kg*4+reg=co -> 4 consecutive co, b64 packs
                const int xs = px ^ ((px >> 1) & 1);
                const int eo = (py*33 + xs)*16 + kg*4;
                _Float16 hh[4], ll[4];
                #pragma unroll
                for (int r = 0; r < 4; ++r) {
                    float v = c[r] + b4[r];
                    v = fmaxf(v, 0.2f*v);          // leaky
                    _Float16 hi = (_Float16)v;
                    hh[r] = hi; ll[r] = (_Float16)(v - (float)hi);
                }
                *(uint2*)&s_x1[0][eo] = *(uint2*)hh;
                *(uint2*)&s_x1[1][eo] = *(uint2*)ll;
            }
        }
        __syncthreads();   // x1 + B-hi ready

        // ---- conv2 pass-hi: AhBh + AlBh per tap ----
        #pragma unroll
        for (int tap = 0; tap < 9; ++tap) {
            const int kh = tap/3, kw = tap%3;
            const int xr = 2*px2 + kw;
            const int xs = xr ^ ((xr >> 1) & 1);
            const int ae = ((2*py2 + kh)*33 + xs)*16 + hf2*8;
            f16x8 Ah = *(const f16x8*)&s_x1[0][ae];
            f16x8 Al = *(const f16x8*)&s_x1[1][ae];
            f16x8 Bh = *(const f16x8*)&s_B[co2*152 + tap*16 + hf2*8];
            acc = __builtin_amdgcn_mfma_f32_32x32x16_f16(Ah, Bh, acc, 0, 0, 0);
            acc = __builtin_amdgcn_mfma_f32_32x32x16_f16(Al, Bh, acc, 0, 0, 0);
        }
        __syncthreads();   // pass-hi done reading s_B

        // ---- stage B lo-plane ----
        {
            const uint32_t* src = W2u + (size_t)(ch*2 + 1)*4864;
            for (int i = tid; i < 4864; i += 512) sBu[i] = src[i];
        }
        __syncthreads();   // B-lo ready (x1 untouched)

        // ---- conv2 pass-lo: AhBl per tap ----
        #pragma unroll
        for (int tap = 0; tap < 9; ++tap) {
            const int kh = tap/3, kw = tap%3;
            const int xr = 2*px2 + kw;
            const int xs = xr ^ ((xr >> 1) & 1);
            const int ae = ((2*py2 + kh)*33 + xs)*16 + hf2*8;
            f16x8 Ah = *(const f16x8*)&s_x1[0][ae];
            f16x8 Bl = *(const f16x8*)&s_B[co2*152 + tap*16 + hf2*8];
            acc = __builtin_amdgcn_mfma_f32_32x32x16_f16(Ah, Bl, acc, 0, 0, 0);
        }
        __syncthreads();   // chunk done: s_x1 / s_B free
    }

    // ---- bias + leaky + GAP partial (layout-agnostic: sum all regs) ----
    {
        const float b2 = c2b[co2];
        float s = 0.f;
        #pragma unroll
        for (int r = 0; r < 16; ++r) {
            float v = acc[r] + b2;
            s += fmaxf(v, 0.2f*v);
        }
        s += __shfl_xor(s, 32);
        if (l < 32) s_part[w][l] = s;
    }
    __syncthreads();
    if (tid < 64) {
        float g = 0.f;
        #pragma unroll
        for (int m = 0; m < 4; ++m) g += s_part[m*2 + (tid >> 5)][tid & 31];
        gapp[(size_t)(n*2 + h)*64 + tid] = g;
    }
}

// ---------------------------------------------------------------------------
// kScore: per image (2048 blocks x 128 thr). GAP combine, proj, scorer MLP.
// ---------------------------------------------------------------------------
__global__ __launch_bounds__(128) void kScore(
    const float* __restrict__ gapp,
    const float* __restrict__ pw,  const float* __restrict__ pb,
    const float* __restrict__ v1w, const float* __restrict__ v1b,
    const float* __restrict__ v2w, const float* __restrict__ v2b,
    const float* __restrict__ v3w, const float* __restrict__ v3b,
    float* __restrict__ feats, float* __restrict__ scores)
{
    __shared__ float s_gap[64], s_f[128], s_h[128], s_red[2];
    const int n = blockIdx.x, tid = threadIdx.x;

    if (tid < 64)
        s_gap[tid] = (gapp[(size_t)n*128 + tid] + gapp[(size_t)n*128 + 64 + tid])
                     * (1.f/256.f);
    __syncthreads();
    {
        float a = pb[tid];
        #pragma unroll 8
        for (int m = 0; m < 64; ++m) a += s_gap[m]*pw[m*128 + tid];
        feats[(size_t)n*128 + tid] = a;
        s_f[tid] = a;
    }
    __syncthreads();
    {
        float a = v1b[tid];
        #pragma unroll 8
        for (int m = 0; m < 128; ++m) a += s_f[m]*v1w[m*128 + tid];
        s_h[tid] = LEAKY(a);
    }
    __syncthreads();
    {
        float a = v2b[tid];
        #pragma unroll 8
        for (int m = 0; m < 128; ++m) a += s_h[m]*v2w[m*128 + tid];
        a = LEAKY(a);
        s_f[tid] = a * v3w[tid];
    }
    __syncthreads();
    {
        float p = s_f[tid];
        #pragma unroll
        for (int off = 32; off; off >>= 1) p += __shfl_xor(p, off);
        if ((tid & 63) == 0) s_red[tid >> 6] = p;
    }
    __syncthreads();
    if (tid == 0) scores[n] = tanhf(s_red[0] + s_red[1] + v3b[0]);
}

// ---------------------------------------------------------------------------
// kArgGather: per-batch argmax (first-index tie-break) + gather feats row
// ---------------------------------------------------------------------------
__global__ __launch_bounds__(128) void kArgGather(
    const float* __restrict__ scores, const float* __restrict__ feats,
    float* __restrict__ res)
{
    __shared__ int s_idx;
    const int b = blockIdx.x, tid = threadIdx.x;
    if (tid < 64) {
        float v = scores[b*64 + tid];
        int   i = tid;
        #pragma unroll
        for (int off = 32; off; off >>= 1) {
            float ov = __shfl_xor(v, off);
            int   oi = __shfl_xor(i, off);
            if (ov > v || (ov == v && oi < i)) { v = ov; i = oi; }
        }
        if (tid == 0) s_idx = i;
    }
    __syncthreads();
    const int idx = s_idx;
    res[b*128 + tid] = feats[((size_t)b*64 + idx)*128 + tid];
}

// ---------------------------------------------------------------------------
// kDecode: decoder (fp32). bid%8 -> same d2 column slice per XCD.
// ---------------------------------------------------------------------------
__global__ __launch_bounds__(512) void kDecode(
    const float* __restrict__ res,
    const float* __restrict__ d1w, const float* __restrict__ d1b,
    const float* __restrict__ d2w, const float* __restrict__ d2b,
    float* __restrict__ out)
{
    __shared__ float s_res[128];
    __shared__ float s_h[512];
    const int bid = blockIdx.x;
    const int b = bid >> 3, ot = bid & 7;
    const int tid = threadIdx.x;

    if (tid < 128) s_res[tid] = res[b*128 + tid];
    __syncthreads();
    {
        float a = d1b[tid];
        #pragma unroll 8
        for (int m = 0; m < 128; ++m) a += s_res[m]*d1w[m*512 + tid];
        s_h[tid] = LEAKY(a);
    }
    __syncthreads();
    const int o = ot*512 + tid;
    float a = d2b[o];
    for (int k = 0; k < 512; k += 4) {
        float4 h4 = *(const float4*)&s_h[k];
        a += h4.x*d2w[(size_t)(k+0)*4096 + o];
        a += h4.y*d2w[(size_t)(k+1)*4096 + o];
        a += h4.z*d2w[(size_t)(k+2)*4096 + o];
        a += h4.w*d2w[(size_t)(k+3)*4096 + o];
    }
    out[(size_t)b*4096 + o] = tanhf(a);
}

// ---------------------------------------------------------------------------
extern "C" void kernel_launch(void* const* d_in, const int* in_sizes, int n_in,
                              void* d_out, int out_size, void* d_ws, size_t ws_size,
                              hipStream_t stream)
{
    const float* texts  = (const float*)d_in[0];
    const float* styles = (const float*)d_in[1];
    const float* c1w = (const float*)d_in[2];
    const float* c1b = (const float*)d_in[3];
    const float* c2w = (const float*)d_in[4];
    const float* c2b = (const float*)d_in[5];
    const float* pw  = (const float*)d_in[6];
    const float* pb  = (const float*)d_in[7];
    const float* v1w = (const float*)d_in[8];
    const float* v1b = (const float*)d_in[9];
    const float* v2w = (const float*)d_in[10];
    const float* v2b = (const float*)d_in[11];
    const float* v3w = (const float*)d_in[12];
    const float* v3b = (const float*)d_in[13];
    const float* d1w = (const float*)d_in[14];
    const float* d1b = (const float*)d_in[15];
    const float* d2w = (const float*)d_in[16];
    const float* d2b = (const float*)d_in[17];

    float* ws     = (float*)d_ws;
    float* feats  = ws + WS_FEATS;
    float* scores = ws + WS_SCORES;
    float* res    = ws + WS_RES;
    float* gapp   = ws + WS_GAPP;

    kPack<<<dim3(16), dim3(256), 0, stream>>>(c1w, c2w, ws);
    kConv<<<dim3(4096), dim3(512), 0, stream>>>(
        texts, styles, c1b, c2b, (const float*)ws, gapp);
    kScore<<<dim3(2048), dim3(128), 0, stream>>>(
        gapp, pw, pb, v1w, v1b, v2w, v2b, v3w, v3b, feats, scores);
    kArgGather<<<dim3(32), dim3(128), 0, stream>>>(scores, feats, res);
    kDecode<<<dim3(256), dim3(512), 0, stream>>>(res, d1w, d1b, d2w, d2b,
                                                 (float*)d_out);
}

// Round 10
// 215.720 us; speedup vs baseline: 3.8908x; 1.0094x over previous
//
#include <hip/hip_runtime.h>
#include <cstddef>
#include <cstdint>

#define LEAKY(x) ((x) > 0.f ? (x) : 0.2f*(x))

typedef _Float16 f16x8  __attribute__((ext_vector_type(8)));
typedef float    f32x4  __attribute__((ext_vector_type(4)));
typedef float    f32x16 __attribute__((ext_vector_type(16)));

// ws float-offsets
#define WS_FEATS   0            // 32*64*128 = 262144 floats
#define WS_SCORES  262144       // 2048
#define WS_RES     264192       // 4096
#define WS_W2      268288       // fp16: 2ch*2pl*64*152 = 38912 halfs (19456 float slots)
#define WS_W1M     287744       // fp16: 2pl*32co*32k = 2048 halfs (1024 float slots)
#define WS_GAPP    288768       // 2048 imgs * 2 halves * 64 ch = 262144 floats

// ---------------------------------------------------------------------------
// kPack (16 blocks x 256):
//  W2[chunk][plane][co64][152], k = tap*16 + ci_in_chunk (k>=144 zero);
//    row stride 152 halfs = 19 granules (odd) -> B-reads cover all LDS slots.
//  W1M[plane][co32][k32], k = kh*8 + kw*2 + ci for kh<3,kw<3; ZERO at
//    k%8 in {6,7} and k>=24 -- these zeros make the conv1 B-side's
//    don't-care input bytes harmless (A zero kills the product).
// ---------------------------------------------------------------------------
__global__ void kPack(const float* __restrict__ c1w, const float* __restrict__ c2w,
                      float* __restrict__ ws)
{
    _Float16* W2 = (_Float16*)(ws + WS_W2);
    _Float16* W1 = (_Float16*)(ws + WS_W1M);
    const int t = blockIdx.x*256 + threadIdx.x;
    for (int i = t; i < 2*64*152; i += 16*256) {
        int k = i % 152, rest = i / 152;
        int co = rest & 63, c = rest >> 6;
        _Float16 h = (_Float16)0.f, lo = (_Float16)0.f;
        if (k < 144) {
            int tap = k >> 4, cil = k & 15;
            float wv = c2w[(co*32 + c*16 + cil)*9 + tap];
            h  = (_Float16)wv;
            lo = (_Float16)(wv - (float)h);
        }
        W2[((size_t)(c*2 + 0)*64 + co)*152 + k] = h;
        W2[((size_t)(c*2 + 1)*64 + co)*152 + k] = lo;
    }
    if (t < 2048) {
        int pl = t >> 10, rest = t & 1023;
        int co = rest >> 5, k = rest & 31;
        int kh = k >> 3, j = k & 7, kw = j >> 1, ci = j & 1;
        float wv = 0.f;
        if (kh < 3 && kw < 3) wv = c1w[co*18 + ci*9 + kh*3 + kw];
        _Float16 hi = (_Float16)wv;
        W1[t] = pl ? (_Float16)(wv - (float)hi) : hi;
    }
}

// ---------------------------------------------------------------------------
// kConv: HALF image per block. bid = n*2 + h (4096 blocks x 512 thr).
//   Input staged fp16 hi/lo NHWC-interleaved in[row][x][ci]; conv1 is
//   implicit-GEMM on mfma_f32_16x16x32_f16 (3-MFMA split, B-frag = direct
//   16B read of the interleaved patch; A-frags read per-lane from global).
//   conv2: 32x32x16 f16, B staged one plane at a time (r8 schedule).
//   GAP partials -> gapp[n][h][64]; scorer in kScore.
// LDS = 74400 B -> block size 74752 (r8's proven 2-blocks/CU point).
// s_part aliased onto s_in (union) -- s_part first written well after the
// last s_in read, with barriers between. No global_load_lds, 512 thr,
// bare launch_bounds (r5-r7 spill lessons).
// ---------------------------------------------------------------------------
__global__ __launch_bounds__(512) void kConv(
    const float* __restrict__ texts, const float* __restrict__ styles,
    const float* __restrict__ c1b, const float* __restrict__ c2b,
    const float* __restrict__ wsro, float* __restrict__ gapp)
{
    __shared__ __align__(16) union {
        _Float16 in[2][35][68][2];                         // 19,040 B
        float    part[8][32];                              // (aliased, used last)
    } s_u;
    __shared__ __align__(16) _Float16 s_x1[2][17*33*16];   // 35,904 B (hi, lo)
    __shared__ __align__(16) _Float16 s_B[64*152];         // 19,456 B (one plane)

    const int bid = blockIdx.x, tid = threadIdx.x;
    const int n = bid >> 1, h = bid & 1;
    const int w = tid >> 6, l = tid & 63;

    // zero x1 (col 32 pad; h=1's local row 16 stays zero = true conv2 pad)
    {
        const uint4 z4 = {0u,0u,0u,0u};
        uint4* z = (uint4*)&s_x1[0][0];
        for (int i = tid; i < 2244; i += 512) z[i] = z4;
        if (tid < 70) {           // s_in pad cols x=64..67, both planes
            int pl = tid >= 35, row = pl ? tid - 35 : tid;
            *(uint4*)&s_u.in[pl][row][64][0] = z4;
        }
    }
    // stage input rows h*32..h*32+34, fp16 hi/lo interleaved (rows>=64 zero)
    for (int u = tid; u < 560; u += 512) {
        const int row = u >> 4, g = u & 15;
        const int grow = h*32 + row;
        float4 tv = {0.f,0.f,0.f,0.f}, sv = {0.f,0.f,0.f,0.f};
        if (grow < 64) {
            tv = *(const float4*)&texts [(size_t)n*4096 + grow*64 + g*4];
            sv = *(const float4*)&styles[(size_t)n*4096 + grow*64 + g*4];
        }
        float vals[8] = {tv.x, sv.x, tv.y, sv.y, tv.z, sv.z, tv.w, sv.w};
        _Float16 hh[8], ll[8];
        #pragma unroll
        for (int j = 0; j < 8; ++j) {
            _Float16 hi = (_Float16)vals[j];
            hh[j] = hi; ll[j] = (_Float16)(vals[j] - (float)hi);
        }
        *(uint4*)&s_u.in[0][row][g*4][0] = *(uint4*)hh;
        *(uint4*)&s_u.in[1][row][g*4][0] = *(uint4*)ll;
    }
    __syncthreads();

    const uint32_t* W2u = (const uint32_t*)(wsro + WS_W2);
    const _Float16* W1g = (const _Float16*)(wsro + WS_W1M);
    uint32_t* sBu = (uint32_t*)&s_B[0];

    f32x16 acc;
    #pragma unroll
    for (int r = 0; r < 16; ++r) acc[r] = 0.f;

    // conv2 roles (r8)
    const int mt = w >> 1, nh = w & 1;
    const int posl = mt*32 + (l & 31);
    const int py2 = posl >> 4, px2 = posl & 15;
    const int hf2 = l >> 5;
    const int co2 = nh*32 + (l & 31);
    // conv1 roles
    const int kg = l >> 4, m16 = l & 15;
    const int NT = 34 - 2*h;   // h=1 skips py=16 (x1 row 16 = zero pad)

    for (int ch = 0; ch < 2; ++ch) {
        // ---- stage B hi-plane ----
        {
            const uint32_t* src = W2u + (size_t)(ch*2 + 0)*4864;
            for (int i = tid; i < 4864; i += 512) sBu[i] = src[i];
        }
        // ---- conv1 via MFMA: 16 co of this chunk, pos-tiles of 16 ----
        {
            // per-lane A-fragments straight from global (L2-hot, 16B aligned)
            f16x8 a_h = *(const f16x8*)&W1g[(0*32 + ch*16 + m16)*32 + kg*8];
            f16x8 a_l = *(const f16x8*)&W1g[(1*32 + ch*16 + m16)*32 + kg*8];
            float4 b4 = *(const float4*)&c1b[ch*16 + kg*4];
            for (int t = w; t < NT; t += 8) {
                const int py = t >> 1, px = (t & 1)*16 + m16;
                const int row = (kg < 3) ? (2*py + kg) : 0;  // kg=3: A rows zero
                const _Float16* bp0 = &s_u.in[0][row][2*px][0];
                const _Float16* bp1 = &s_u.in[1][row][2*px][0];
                f16x8 b_h, b_l;   // 8B-aligned -> two b64 reads each
                ((uint2*)&b_h)[0] = *(const uint2*)bp0;
                ((uint2*)&b_h)[1] = *(const uint2*)(bp0 + 4);
                ((uint2*)&b_l)[0] = *(const uint2*)bp1;
                ((uint2*)&b_l)[1] = *(const uint2*)(bp1 + 4);
                f32x4 c = {0.f,0.f,0.f,0.f};
                c = __builtin_amdgcn_mfma_f32_16x16x32_f16(a_l, b_h, c, 0, 0, 0);
                c = __builtin_amdgcn_mfma_f32_16x16x32_f16(a_h, b_l, c, 0, 0, 0);
                c = __builtin_amdgcn_mfma_f32_16x16x32_f16(a_h, b_h, c, 0, 0, 0);
                // C: col=l&15=pos, row=kg*4+reg=co -> 4 consecutive co, b64 packs
                const int xs = px ^ ((px >> 1) & 1);
                const int eo = (py*33 + xs)*16 + kg*4;
                _Float16 hh[4], ll[4];
                #pragma unroll
                for (int r = 0; r < 4; ++r) {
                    float v = c[r] + b4[r];
                    v = fmaxf(v, 0.2f*v);          // leaky
                    _Float16 hi = (_Float16)v;
                    hh[r] = hi; ll[r] = (_Float16)(v - (float)hi);
                }
                *(uint2*)&s_x1[0][eo] = *(uint2*)hh;
                *(uint2*)&s_x1[1][eo] = *(uint2*)ll;
            }
        }
        __syncthreads();   // x1 + B-hi ready

        // ---- conv2 pass-hi: AhBh + AlBh per tap ----
        #pragma unroll
        for (int tap = 0; tap < 9; ++tap) {
            const int kh = tap/3, kw = tap%3;
            const int xr = 2*px2 + kw;
            const int xs = xr ^ ((xr >> 1) & 1);
            const int ae = ((2*py2 + kh)*33 + xs)*16 + hf2*8;
            f16x8 Ah = *(const f16x8*)&s_x1[0][ae];
            f16x8 Al = *(const f16x8*)&s_x1[1][ae];
            f16x8 Bh = *(const f16x8*)&s_B[co2*152 + tap*16 + hf2*8];
            acc = __builtin_amdgcn_mfma_f32_32x32x16_f16(Ah, Bh, acc, 0, 0, 0);
            acc = __builtin_amdgcn_mfma_f32_32x32x16_f16(Al, Bh, acc, 0, 0, 0);
        }
        __syncthreads();   // pass-hi done reading s_B

        // ---- stage B lo-plane ----
        {
            const uint32_t* src = W2u + (size_t)(ch*2 + 1)*4864;
            for (int i = tid; i < 4864; i += 512) sBu[i] = src[i];
        }
        __syncthreads();   // B-lo ready (x1 untouched)

        // ---- conv2 pass-lo: AhBl per tap ----
        #pragma unroll
        for (int tap = 0; tap < 9; ++tap) {
            const int kh = tap/3, kw = tap%3;
            const int xr = 2*px2 + kw;
            const int xs = xr ^ ((xr >> 1) & 1);
            const int ae = ((2*py2 + kh)*33 + xs)*16 + hf2*8;
            f16x8 Ah = *(const f16x8*)&s_x1[0][ae];
            f16x8 Bl = *(const f16x8*)&s_B[co2*152 + tap*16 + hf2*8];
            acc = __builtin_amdgcn_mfma_f32_32x32x16_f16(Ah, Bl, acc, 0, 0, 0);
        }
        __syncthreads();   // chunk done: s_x1 / s_B free
    }

    // ---- bias + leaky + GAP partial (layout-agnostic: sum all regs) ----
    {
        const float b2 = c2b[co2];
        float s = 0.f;
        #pragma unroll
        for (int r = 0; r < 16; ++r) {
            float v = acc[r] + b2;
            s += fmaxf(v, 0.2f*v);
        }
        s += __shfl_xor(s, 32);
        if (l < 32) s_u.part[w][l] = s;    // s_in dead by now (barriers between)
    }
    __syncthreads();
    if (tid < 64) {
        float g = 0.f;
        #pragma unroll
        for (int m = 0; m < 4; ++m) g += s_u.part[m*2 + (tid >> 5)][tid & 31];
        gapp[(size_t)(n*2 + h)*64 + tid] = g;
    }
}

// ---------------------------------------------------------------------------
// kScore: per image (2048 blocks x 128 thr). GAP combine, proj, scorer MLP.
// ---------------------------------------------------------------------------
__global__ __launch_bounds__(128) void kScore(
    const float* __restrict__ gapp,
    const float* __restrict__ pw,  const float* __restrict__ pb,
    const float* __restrict__ v1w, const float* __restrict__ v1b,
    const float* __restrict__ v2w, const float* __restrict__ v2b,
    const float* __restrict__ v3w, const float* __restrict__ v3b,
    float* __restrict__ feats, float* __restrict__ scores)
{
    __shared__ float s_gap[64], s_f[128], s_h[128], s_red[2];
    const int n = blockIdx.x, tid = threadIdx.x;

    if (tid < 64)
        s_gap[tid] = (gapp[(size_t)n*128 + tid] + gapp[(size_t)n*128 + 64 + tid])
                     * (1.f/256.f);
    __syncthreads();
    {
        float a = pb[tid];
        #pragma unroll 8
        for (int m = 0; m < 64; ++m) a += s_gap[m]*pw[m*128 + tid];
        feats[(size_t)n*128 + tid] = a;
        s_f[tid] = a;
    }
    __syncthreads();
    {
        float a = v1b[tid];
        #pragma unroll 8
        for (int m = 0; m < 128; ++m) a += s_f[m]*v1w[m*128 + tid];
        s_h[tid] = LEAKY(a);
    }
    __syncthreads();
    {
        float a = v2b[tid];
        #pragma unroll 8
        for (int m = 0; m < 128; ++m) a += s_h[m]*v2w[m*128 + tid];
        a = LEAKY(a);
        s_f[tid] = a * v3w[tid];
    }
    __syncthreads();
    {
        float p = s_f[tid];
        #pragma unroll
        for (int off = 32; off; off >>= 1) p += __shfl_xor(p, off);
        if ((tid & 63) == 0) s_red[tid >> 6] = p;
    }
    __syncthreads();
    if (tid == 0) scores[n] = tanhf(s_red[0] + s_red[1] + v3b[0]);
}

// ---------------------------------------------------------------------------
// kArgGather: per-batch argmax (first-index tie-break) + gather feats row
// ---------------------------------------------------------------------------
__global__ __launch_bounds__(128) void kArgGather(
    const float* __restrict__ scores, const float* __restrict__ feats,
    float* __restrict__ res)
{
    __shared__ int s_idx;
    const int b = blockIdx.x, tid = threadIdx.x;
    if (tid < 64) {
        float v = scores[b*64 + tid];
        int   i = tid;
        #pragma unroll
        for (int off = 32; off; off >>= 1) {
            float ov = __shfl_xor(v, off);
            int   oi = __shfl_xor(i, off);
            if (ov > v || (ov == v && oi < i)) { v = ov; i = oi; }
        }
        if (tid == 0) s_idx = i;
    }
    __syncthreads();
    const int idx = s_idx;
    res[b*128 + tid] = feats[((size_t)b*64 + idx)*128 + tid];
}

// ---------------------------------------------------------------------------
// kDecode: decoder (fp32). bid%8 -> same d2 column slice per XCD.
// ---------------------------------------------------------------------------
__global__ __launch_bounds__(512) void kDecode(
    const float* __restrict__ res,
    const float* __restrict__ d1w, const float* __restrict__ d1b,
    const float* __restrict__ d2w, const float* __restrict__ d2b,
    float* __restrict__ out)
{
    __shared__ float s_res[128];
    __shared__ float s_h[512];
    const int bid = blockIdx.x;
    const int b = bid >> 3, ot = bid & 7;
    const int tid = threadIdx.x;

    if (tid < 128) s_res[tid] = res[b*128 + tid];
    __syncthreads();
    {
        float a = d1b[tid];
        #pragma unroll 8
        for (int m = 0; m < 128; ++m) a += s_res[m]*d1w[m*512 + tid];
        s_h[tid] = LEAKY(a);
    }
    __syncthreads();
    const int o = ot*512 + tid;
    float a = d2b[o];
    for (int k = 0; k < 512; k += 4) {
        float4 h4 = *(const float4*)&s_h[k];
        a += h4.x*d2w[(size_t)(k+0)*4096 + o];
        a += h4.y*d2w[(size_t)(k+1)*4096 + o];
        a += h4.z*d2w[(size_t)(k+2)*4096 + o];
        a += h4.w*d2w[(size_t)(k+3)*4096 + o];
    }
    out[(size_t)b*4096 + o] = tanhf(a);
}

// ---------------------------------------------------------------------------
extern "C" void kernel_launch(void* const* d_in, const int* in_sizes, int n_in,
                              void* d_out, int out_size, void* d_ws, size_t ws_size,
                              hipStream_t stream)
{
    const float* texts  = (const float*)d_in[0];
    const float* styles = (const float*)d_in[1];
    const float* c1w = (const float*)d_in[2];
    const float* c1b = (const float*)d_in[3];
    const float* c2w = (const float*)d_in[4];
    const float* c2b = (const float*)d_in[5];
    const float* pw  = (const float*)d_in[6];
    const float* pb  = (const float*)d_in[7];
    const float* v1w = (const float*)d_in[8];
    const float* v1b = (const float*)d_in[9];
    const float* v2w = (const float*)d_in[10];
    const float* v2b = (const float*)d_in[11];
    const float* v3w = (const float*)d_in[12];
    const float* v3b = (const float*)d_in[13];
    const float* d1w = (const float*)d_in[14];
    const float* d1b = (const float*)d_in[15];
    const float* d2w = (const float*)d_in[16];
    const float* d2b = (const float*)d_in[17];

    float* ws     = (float*)d_ws;
    float* feats  = ws + WS_FEATS;
    float* scores = ws + WS_SCORES;
    float* res    = ws + WS_RES;
    float* gapp   = ws + WS_GAPP;

    kPack<<<dim3(16), dim3(256), 0, stream>>>(c1w, c2w, ws);
    kConv<<<dim3(4096), dim3(512), 0, stream>>>(
        texts, styles, c1b, c2b, (const float*)ws, gapp);
    kScore<<<dim3(2048), dim3(128), 0, stream>>>(
        gapp, pw, pb, v1w, v1b, v2w, v2b, v3w, v3b, feats, scores);
    kArgGather<<<dim3(32), dim3(128), 0, stream>>>(scores, feats, res);
    kDecode<<<dim3(256), dim3(512), 0, stream>>>(res, d1w, d1b, d2w, d2b,
                                                 (float*)d_out);
}

// Round 11
// 153.487 us; speedup vs baseline: 5.4684x; 1.4055x over previous
//
#include <hip/hip_runtime.h>
#include <cstddef>
#include <cstdint>

#define LEAKY(x) ((x) > 0.f ? (x) : 0.2f*(x))

typedef _Float16 f16x8  __attribute__((ext_vector_type(8)));
typedef float    f32x4  __attribute__((ext_vector_type(4)));
typedef float    f32x16 __attribute__((ext_vector_type(16)));

// ws float-offsets
#define WS_FEATS   0            // 32*64*128 = 262144 floats
#define WS_SCORES  262144       // 2048
#define WS_RES     264192       // 4096
#define WS_W2      268288       // fp16: 2ch*2pl*64*152 = 38912 halfs (19456 float slots)
#define WS_W1M     287744       // fp16: 2pl*32co*32k = 2048 halfs (1024 float slots)
#define WS_GAPP    288768       // 2048 imgs * 4 quarters * 64 ch = 524288 floats

// ---------------------------------------------------------------------------
// kPack (16 blocks x 256):
//  W2[chunk][plane][co64][152], k = tap*16 + ci_in_chunk (k>=144 zero);
//    row stride 152 halfs = 19 granules (odd) -> B-reads cover all LDS slots.
//  W1M[plane][co32][k32], k = kh*8 + kw*2 + ci for kh<3,kw<3; ZERO at
//    k%8 in {6,7} and k>=24 (don't-care input bytes killed by zero A).
// ---------------------------------------------------------------------------
__global__ void kPack(const float* __restrict__ c1w, const float* __restrict__ c2w,
                      float* __restrict__ ws)
{
    _Float16* W2 = (_Float16*)(ws + WS_W2);
    _Float16* W1 = (_Float16*)(ws + WS_W1M);
    const int t = blockIdx.x*256 + threadIdx.x;
    for (int i = t; i < 2*64*152; i += 16*256) {
        int k = i % 152, rest = i / 152;
        int co = rest & 63, c = rest >> 6;
        _Float16 h = (_Float16)0.f, lo = (_Float16)0.f;
        if (k < 144) {
            int tap = k >> 4, cil = k & 15;
            float wv = c2w[(co*32 + c*16 + cil)*9 + tap];
            h  = (_Float16)wv;
            lo = (_Float16)(wv - (float)h);
        }
        W2[((size_t)(c*2 + 0)*64 + co)*152 + k] = h;
        W2[((size_t)(c*2 + 1)*64 + co)*152 + k] = lo;
    }
    if (t < 2048) {
        int pl = t >> 10, rest = t & 1023;
        int co = rest >> 5, k = rest & 31;
        int kh = k >> 3, j = k & 7, kw = j >> 1, ci = j & 1;
        float wv = 0.f;
        if (kh < 3 && kw < 3) wv = c1w[co*18 + ci*9 + kh*3 + kw];
        _Float16 hi = (_Float16)wv;
        W1[t] = pl ? (_Float16)(wv - (float)hi) : hi;
    }
}

// ---------------------------------------------------------------------------
// kConv: QUARTER image per block. bid = n*4 + q (8192 blocks x 256 thr).
//   Quarter q: conv2 out rows 4q..4q+3; x1 local rows 0..8 (halo; q=3's
//   row 8 = global row 32 stays zero); input rows 16q..16q+18.
//   conv1: implicit-GEMM mfma_f32_16x16x32_f16 (3-MFMA hi/lo split).
//   conv2: mfma_f32_32x32x16_f16, B one plane at a time.
// x1 layout [pl][hf][row][parity][q17][8ci]: the ci dim is split into two
// 8-ci planes (hf) and x into even/odd (parity) so conv2's 16-lane row reads
// stride 16B -> all 8 LDS slots covered = conflict-free (r10 had 4-way:
// 1.36e7 conflict cycles = ~22us/CU). conv1 writes also conflict-free.
// LDS = 49376 B -> 3 blocks/CU by LDS. 256 thr, bare bounds (spill lessons).
// ---------------------------------------------------------------------------
__global__ __launch_bounds__(256) void kConv(
    const float* __restrict__ texts, const float* __restrict__ styles,
    const float* __restrict__ c1b, const float* __restrict__ c2b,
    const float* __restrict__ wsro, float* __restrict__ gapp)
{
    __shared__ __align__(16) union {
        _Float16 in[2][19][68][2];                          // 10,336 B
        float    part[4][32];                               // (aliased, used last)
    } s_u;
    __shared__ __align__(16) _Float16 s_x1[2][2][9][2][17][8]; // 19,584 B
    __shared__ __align__(16) _Float16 s_B[64*152];             // 19,456 B

    const int bid = blockIdx.x, tid = threadIdx.x;
    const int n = bid >> 2, q = bid & 3;
    const int w = tid >> 6, l = tid & 63;

    // zero x1 (pads: parity0 q16 = col 32; q=3's row 8)
    {
        const uint4 z4 = {0u,0u,0u,0u};
        uint4* z = (uint4*)&s_x1[0][0][0][0][0][0];
        for (int i = tid; i < 1224; i += 256) z[i] = z4;
        if (tid < 38) {           // s_in pad cols x=64..67, both planes
            int pl = tid >= 19, row = pl ? tid - 19 : tid;
            *(uint4*)&s_u.in[pl][row][64][0] = z4;
        }
    }
    // stage input rows 16q..16q+18, fp16 hi/lo interleaved (rows>=64 zero)
    for (int u = tid; u < 304; u += 256) {
        const int row = u >> 4, g = u & 15;
        const int grow = q*16 + row;
        float4 tv = {0.f,0.f,0.f,0.f}, sv = {0.f,0.f,0.f,0.f};
        if (grow < 64) {
            tv = *(const float4*)&texts [(size_t)n*4096 + grow*64 + g*4];
            sv = *(const float4*)&styles[(size_t)n*4096 + grow*64 + g*4];
        }
        float vals[8] = {tv.x, sv.x, tv.y, sv.y, tv.z, sv.z, tv.w, sv.w};
        _Float16 hh[8], ll[8];
        #pragma unroll
        for (int j = 0; j < 8; ++j) {
            _Float16 hi = (_Float16)vals[j];
            hh[j] = hi; ll[j] = (_Float16)(vals[j] - (float)hi);
        }
        *(uint4*)&s_u.in[0][row][g*4][0] = *(uint4*)hh;
        *(uint4*)&s_u.in[1][row][g*4][0] = *(uint4*)ll;
    }
    __syncthreads();

    const uint32_t* W2u = (const uint32_t*)(wsro + WS_W2);
    const _Float16* W1g = (const _Float16*)(wsro + WS_W1M);
    uint32_t* sBu = (uint32_t*)&s_B[0];

    f32x16 acc;
    #pragma unroll
    for (int r = 0; r < 16; ++r) acc[r] = 0.f;

    // conv2 roles: 4 waves = 2 M-tiles x 2 N-halves
    const int mt = w >> 1, nh = w & 1;
    const int posl = mt*32 + (l & 31);
    const int py2 = posl >> 4, px2 = posl & 15;   // local rows 0..3
    const int hf2 = l >> 5;
    const int co2 = nh*32 + (l & 31);
    // conv1 roles
    const int kg = l >> 4, m16 = l & 15;
    const int NT = (q == 3) ? 16 : 18;   // q=3 skips py=8 (x1 row 8 = zero pad)

    for (int ch = 0; ch < 2; ++ch) {
        // ---- stage B hi-plane (overlaps conv1 below, same barrier) ----
        {
            const uint32_t* src = W2u + (size_t)(ch*2 + 0)*4864;
            for (int i = tid; i < 4864; i += 256) sBu[i] = src[i];
        }
        // ---- conv1 via MFMA: 16 co of this chunk, 16-pos tiles ----
        {
            f16x8 a_h = *(const f16x8*)&W1g[(0*32 + ch*16 + m16)*32 + kg*8];
            f16x8 a_l = *(const f16x8*)&W1g[(1*32 + ch*16 + m16)*32 + kg*8];
            float4 b4 = *(const float4*)&c1b[ch*16 + kg*4];
            for (int t = w; t < NT; t += 4) {
                const int py = t >> 1, px = (t & 1)*16 + m16;
                const int row = (kg < 3) ? (2*py + kg) : 0;  // kg=3: A rows zero
                const _Float16* bp0 = &s_u.in[0][row][2*px][0];
                const _Float16* bp1 = &s_u.in[1][row][2*px][0];
                f16x8 b_h, b_l;
                ((uint2*)&b_h)[0] = *(const uint2*)bp0;
                ((uint2*)&b_h)[1] = *(const uint2*)(bp0 + 4);
                ((uint2*)&b_l)[0] = *(const uint2*)bp1;
                ((uint2*)&b_l)[1] = *(const uint2*)(bp1 + 4);
                f32x4 c = {0.f,0.f,0.f,0.f};
                c = __builtin_amdgcn_mfma_f32_16x16x32_f16(a_l, b_h, c, 0, 0, 0);
                c = __builtin_amdgcn_mfma_f32_16x16x32_f16(a_h, b_l, c, 0, 0, 0);
                c = __builtin_amdgcn_mfma_f32_16x16x32_f16(a_h, b_h, c, 0, 0, 0);
                // C: col=l&15=pos, row=kg*4+reg=co -> 4 consecutive ci
                const int xp = px & 1, xq = px >> 1;
                _Float16 hh[4], ll[4];
                #pragma unroll
                for (int r = 0; r < 4; ++r) {
                    float v = c[r] + b4[r];
                    v = fmaxf(v, 0.2f*v);          // leaky
                    _Float16 hi = (_Float16)v;
                    hh[r] = hi; ll[r] = (_Float16)(v - (float)hi);
                }
                *(uint2*)&s_x1[0][kg >> 1][py][xp][xq][(kg & 1)*4] = *(uint2*)hh;
                *(uint2*)&s_x1[1][kg >> 1][py][xp][xq][(kg & 1)*4] = *(uint2*)ll;
            }
        }
        __syncthreads();   // x1 + B-hi ready

        // ---- conv2 pass-hi: AhBh + AlBh per tap ----
        #pragma unroll
        for (int tap = 0; tap < 9; ++tap) {
            const int kh = tap/3, kw = tap%3;
            const int xr = 2*px2 + kw;
            const int xp = xr & 1, xq = xr >> 1;
            const int r2 = 2*py2 + kh;
            f16x8 Ah = *(const f16x8*)&s_x1[0][hf2][r2][xp][xq][0];
            f16x8 Al = *(const f16x8*)&s_x1[1][hf2][r2][xp][xq][0];
            f16x8 Bh = *(const f16x8*)&s_B[co2*152 + tap*16 + hf2*8];
            acc = __builtin_amdgcn_mfma_f32_32x32x16_f16(Ah, Bh, acc, 0, 0, 0);
            acc = __builtin_amdgcn_mfma_f32_32x32x16_f16(Al, Bh, acc, 0, 0, 0);
        }
        __syncthreads();   // pass-hi done reading s_B

        // ---- stage B lo-plane ----
        {
            const uint32_t* src = W2u + (size_t)(ch*2 + 1)*4864;
            for (int i = tid; i < 4864; i += 256) sBu[i] = src[i];
        }
        __syncthreads();   // B-lo ready (x1 untouched)

        // ---- conv2 pass-lo: AhBl per tap ----
        #pragma unroll
        for (int tap = 0; tap < 9; ++tap) {
            const int kh = tap/3, kw = tap%3;
            const int xr = 2*px2 + kw;
            const int xp = xr & 1, xq = xr >> 1;
            const int r2 = 2*py2 + kh;
            f16x8 Ah = *(const f16x8*)&s_x1[0][hf2][r2][xp][xq][0];
            f16x8 Bl = *(const f16x8*)&s_B[co2*152 + tap*16 + hf2*8];
            acc = __builtin_amdgcn_mfma_f32_32x32x16_f16(Ah, Bl, acc, 0, 0, 0);
        }
        __syncthreads();   // chunk done: s_x1 / s_B free
    }

    // ---- bias + leaky + GAP partial (layout-agnostic: sum all regs) ----
    {
        const float b2 = c2b[co2];
        float s = 0.f;
        #pragma unroll
        for (int r = 0; r < 16; ++r) {
            float v = acc[r] + b2;
            s += fmaxf(v, 0.2f*v);
        }
        s += __shfl_xor(s, 32);
        if (l < 32) s_u.part[w][l] = s;    // s_in dead (barriers in between)
    }
    __syncthreads();
    if (tid < 64) {
        const int nhc = tid >> 5, cl = tid & 31;
        float g = s_u.part[0*2 + nhc][cl] + s_u.part[1*2 + nhc][cl];
        gapp[(size_t)(n*4 + q)*64 + tid] = g;
    }
}

// ---------------------------------------------------------------------------
// kScore: per image (2048 blocks x 128 thr). GAP combine (4 quarters),
// proj, scorer MLP, tanh score.
// ---------------------------------------------------------------------------
__global__ __launch_bounds__(128) void kScore(
    const float* __restrict__ gapp,
    const float* __restrict__ pw,  const float* __restrict__ pb,
    const float* __restrict__ v1w, const float* __restrict__ v1b,
    const float* __restrict__ v2w, const float* __restrict__ v2b,
    const float* __restrict__ v3w, const float* __restrict__ v3b,
    float* __restrict__ feats, float* __restrict__ scores)
{
    __shared__ float s_gap[64], s_f[128], s_h[128], s_red[2];
    const int n = blockIdx.x, tid = threadIdx.x;

    if (tid < 64) {
        const float* gp = &gapp[(size_t)n*256 + tid];
        s_gap[tid] = (gp[0] + gp[64] + gp[128] + gp[192]) * (1.f/256.f);
    }
    __syncthreads();
    {
        float a = pb[tid];
        #pragma unroll 8
        for (int m = 0; m < 64; ++m) a += s_gap[m]*pw[m*128 + tid];
        feats[(size_t)n*128 + tid] = a;
        s_f[tid] = a;
    }
    __syncthreads();
    {
        float a = v1b[tid];
        #pragma unroll 8
        for (int m = 0; m < 128; ++m) a += s_f[m]*v1w[m*128 + tid];
        s_h[tid] = LEAKY(a);
    }
    __syncthreads();
    {
        float a = v2b[tid];
        #pragma unroll 8
        for (int m = 0; m < 128; ++m) a += s_h[m]*v2w[m*128 + tid];
        a = LEAKY(a);
        s_f[tid] = a * v3w[tid];
    }
    __syncthreads();
    {
        float p = s_f[tid];
        #pragma unroll
        for (int off = 32; off; off >>= 1) p += __shfl_xor(p, off);
        if ((tid & 63) == 0) s_red[tid >> 6] = p;
    }
    __syncthreads();
    if (tid == 0) scores[n] = tanhf(s_red[0] + s_red[1] + v3b[0]);
}

// ---------------------------------------------------------------------------
// kArgGather: per-batch argmax (first-index tie-break) + gather feats row
// ---------------------------------------------------------------------------
__global__ __launch_bounds__(128) void kArgGather(
    const float* __restrict__ scores, const float* __restrict__ feats,
    float* __restrict__ res)
{
    __shared__ int s_idx;
    const int b = blockIdx.x, tid = threadIdx.x;
    if (tid < 64) {
        float v = scores[b*64 + tid];
        int   i = tid;
        #pragma unroll
        for (int off = 32; off; off >>= 1) {
            float ov = __shfl_xor(v, off);
            int   oi = __shfl_xor(i, off);
            if (ov > v || (ov == v && oi < i)) { v = ov; i = oi; }
        }
        if (tid == 0) s_idx = i;
    }
    __syncthreads();
    const int idx = s_idx;
    res[b*128 + tid] = feats[((size_t)b*64 + idx)*128 + tid];
}

// ---------------------------------------------------------------------------
// kDecode: decoder (fp32). bid%8 -> same d2 column slice per XCD.
// ---------------------------------------------------------------------------
__global__ __launch_bounds__(512) void kDecode(
    const float* __restrict__ res,
    const float* __restrict__ d1w, const float* __restrict__ d1b,
    const float* __restrict__ d2w, const float* __restrict__ d2b,
    float* __restrict__ out)
{
    __shared__ float s_res[128];
    __shared__ float s_h[512];
    const int bid = blockIdx.x;
    const int b = bid >> 3, ot = bid & 7;
    const int tid = threadIdx.x;

    if (tid < 128) s_res[tid] = res[b*128 + tid];
    __syncthreads();
    {
        float a = d1b[tid];
        #pragma unroll 8
        for (int m = 0; m < 128; ++m) a += s_res[m]*d1w[m*512 + tid];
        s_h[tid] = LEAKY(a);
    }
    __syncthreads();
    const int o = ot*512 + tid;
    float a = d2b[o];
    for (int k = 0; k < 512; k += 4) {
        float4 h4 = *(const float4*)&s_h[k];
        a += h4.x*d2w[(size_t)(k+0)*4096 + o];
        a += h4.y*d2w[(size_t)(k+1)*4096 + o];
        a += h4.z*d2w[(size_t)(k+2)*4096 + o];
        a += h4.w*d2w[(size_t)(k+3)*4096 + o];
    }
    out[(size_t)b*4096 + o] = tanhf(a);
}

// ---------------------------------------------------------------------------
extern "C" void kernel_launch(void* const* d_in, const int* in_sizes, int n_in,
                              void* d_out, int out_size, void* d_ws, size_t ws_size,
                              hipStream_t stream)
{
    const float* texts  = (const float*)d_in[0];
    const float* styles = (const float*)d_in[1];
    const float* c1w = (const float*)d_in[2];
    const float* c1b = (const float*)d_in[3];
    const float* c2w = (const float*)d_in[4];
    const float* c2b = (const float*)d_in[5];
    const float* pw  = (const float*)d_in[6];
    const float* pb  = (const float*)d_in[7];
    const float* v1w = (const float*)d_in[8];
    const float* v1b = (const float*)d_in[9];
    const float* v2w = (const float*)d_in[10];
    const float* v2b = (const float*)d_in[11];
    const float* v3w = (const float*)d_in[12];
    const float* v3b = (const float*)d_in[13];
    const float* d1w = (const float*)d_in[14];
    const float* d1b = (const float*)d_in[15];
    const float* d2w = (const float*)d_in[16];
    const float* d2b = (const float*)d_in[17];

    float* ws     = (float*)d_ws;
    float* feats  = ws + WS_FEATS;
    float* scores = ws + WS_SCORES;
    float* res    = ws + WS_RES;
    float* gapp   = ws + WS_GAPP;

    kPack<<<dim3(16), dim3(256), 0, stream>>>(c1w, c2w, ws);
    kConv<<<dim3(8192), dim3(256), 0, stream>>>(
        texts, styles, c1b, c2b, (const float*)ws, gapp);
    kScore<<<dim3(2048), dim3(128), 0, stream>>>(
        gapp, pw, pb, v1w, v1b, v2w, v2b, v3w, v3b, feats, scores);
    kArgGather<<<dim3(32), dim3(128), 0, stream>>>(scores, feats, res);
    kDecode<<<dim3(256), dim3(512), 0, stream>>>(res, d1w, d1b, d2w, d2b,
                                                 (float*)d_out);
}

// Round 12
// 139.955 us; speedup vs baseline: 5.9971x; 1.0967x over previous
//
#include <hip/hip_runtime.h>
#include <cstddef>
#include <cstdint>

#define LEAKY(x) ((x) > 0.f ? (x) : 0.2f*(x))

typedef _Float16 f16x8  __attribute__((ext_vector_type(8)));
typedef float    f32x4  __attribute__((ext_vector_type(4)));
typedef float    f32x16 __attribute__((ext_vector_type(16)));

// ws float-offsets
#define WS_FEATS   0            // 32*64*128 = 262144 floats
#define WS_SCORES  262144       // 2048
#define WS_RES     264192       // 4096
#define WS_W2      268288       // fp16: 2ch*2pl*64*152 = 38912 halfs (19456 float slots)
#define WS_W1M     287744       // fp16: 2pl*32co*32k = 2048 halfs (1024 float slots)
#define WS_GAPP    288768       // 2048 imgs * 4 quarters * 64 ch = 524288 floats

// ---------------------------------------------------------------------------
// kPack (16 blocks x 256):
//  W2[chunk][plane][co64][152], k = tap*16 + ci_in_chunk (k>=144 zero);
//    row = exactly the 32x32x16 B-operand per-lane fragment stream: lane co
//    reads 16B at tap*16+hf*8 -> conv2 B-frags load straight from global/L2.
//  W1M[plane][co32][k32], k = kh*8 + kw*2 + ci for kh<3,kw<3; ZERO at
//    k%8 in {6,7} and k>=24 (don't-care input bytes killed by zero A).
// ---------------------------------------------------------------------------
__global__ void kPack(const float* __restrict__ c1w, const float* __restrict__ c2w,
                      float* __restrict__ ws)
{
    _Float16* W2 = (_Float16*)(ws + WS_W2);
    _Float16* W1 = (_Float16*)(ws + WS_W1M);
    const int t = blockIdx.x*256 + threadIdx.x;
    for (int i = t; i < 2*64*152; i += 16*256) {
        int k = i % 152, rest = i / 152;
        int co = rest & 63, c = rest >> 6;
        _Float16 h = (_Float16)0.f, lo = (_Float16)0.f;
        if (k < 144) {
            int tap = k >> 4, cil = k & 15;
            float wv = c2w[(co*32 + c*16 + cil)*9 + tap];
            h  = (_Float16)wv;
            lo = (_Float16)(wv - (float)h);
        }
        W2[((size_t)(c*2 + 0)*64 + co)*152 + k] = h;
        W2[((size_t)(c*2 + 1)*64 + co)*152 + k] = lo;
    }
    if (t < 2048) {
        int pl = t >> 10, rest = t & 1023;
        int co = rest >> 5, k = rest & 31;
        int kh = k >> 3, j = k & 7, kw = j >> 1, ci = j & 1;
        float wv = 0.f;
        if (kh < 3 && kw < 3) wv = c1w[co*18 + ci*9 + kh*3 + kw];
        _Float16 hi = (_Float16)wv;
        W1[t] = pl ? (_Float16)(wv - (float)hi) : hi;
    }
}

// ---------------------------------------------------------------------------
// kConv: QUARTER image per block. bid = n*4 + q (8192 blocks x 256 thr).
//   conv1: implicit-GEMM mfma_f32_16x16x32_f16 (3-MFMA hi/lo split),
//          A-frags (weights) per-lane from global.
//   conv2: mfma_f32_32x32x16_f16, SINGLE pass: B-frags (weights, hi+lo)
//          per-lane straight from global (W2 is 76KB -> L2-resident; the
//          packed row IS the B-operand fragment layout). No s_B, no
//          B-staging, 5 barriers/block (was 13).
// x1 layout [pl][hf][row][parity][q17][8ci] (conflict-split, r11).
// LDS = 29,920 B. 256 thr, bare bounds (spill lessons r5-r7).
// ---------------------------------------------------------------------------
__global__ __launch_bounds__(256) void kConv(
    const float* __restrict__ texts, const float* __restrict__ styles,
    const float* __restrict__ c1b, const float* __restrict__ c2b,
    const float* __restrict__ wsro, float* __restrict__ gapp)
{
    __shared__ __align__(16) union {
        _Float16 in[2][19][68][2];                          // 10,336 B
        float    part[4][32];                               // (aliased, used last)
    } s_u;
    __shared__ __align__(16) _Float16 s_x1[2][2][9][2][17][8]; // 19,584 B

    const int bid = blockIdx.x, tid = threadIdx.x;
    const int n = bid >> 2, q = bid & 3;
    const int w = tid >> 6, l = tid & 63;

    // zero x1 (pads: parity0 q16 = col 32; q=3's row 8)
    {
        const uint4 z4 = {0u,0u,0u,0u};
        uint4* z = (uint4*)&s_x1[0][0][0][0][0][0];
        for (int i = tid; i < 1224; i += 256) z[i] = z4;
        if (tid < 38) {           // s_in pad cols x=64..67, both planes
            int pl = tid >= 19, row = pl ? tid - 19 : tid;
            *(uint4*)&s_u.in[pl][row][64][0] = z4;
        }
    }
    // stage input rows 16q..16q+18, fp16 hi/lo interleaved (rows>=64 zero)
    for (int u = tid; u < 304; u += 256) {
        const int row = u >> 4, g = u & 15;
        const int grow = q*16 + row;
        float4 tv = {0.f,0.f,0.f,0.f}, sv = {0.f,0.f,0.f,0.f};
        if (grow < 64) {
            tv = *(const float4*)&texts [(size_t)n*4096 + grow*64 + g*4];
            sv = *(const float4*)&styles[(size_t)n*4096 + grow*64 + g*4];
        }
        float vals[8] = {tv.x, sv.x, tv.y, sv.y, tv.z, sv.z, tv.w, sv.w};
        _Float16 hh[8], ll[8];
        #pragma unroll
        for (int j = 0; j < 8; ++j) {
            _Float16 hi = (_Float16)vals[j];
            hh[j] = hi; ll[j] = (_Float16)(vals[j] - (float)hi);
        }
        *(uint4*)&s_u.in[0][row][g*4][0] = *(uint4*)hh;
        *(uint4*)&s_u.in[1][row][g*4][0] = *(uint4*)ll;
    }
    __syncthreads();

    const _Float16* W2h = (const _Float16*)(wsro + WS_W2);
    const _Float16* W1g = (const _Float16*)(wsro + WS_W1M);

    f32x16 acc;
    #pragma unroll
    for (int r = 0; r < 16; ++r) acc[r] = 0.f;

    // conv2 roles: 4 waves = 2 M-tiles x 2 N-halves
    const int mt = w >> 1, nh = w & 1;
    const int posl = mt*32 + (l & 31);
    const int py2 = posl >> 4, px2 = posl & 15;   // local rows 0..3
    const int hf2 = l >> 5;
    const int co2 = nh*32 + (l & 31);
    // conv1 roles
    const int kg = l >> 4, m16 = l & 15;
    const int NT = (q == 3) ? 16 : 18;   // q=3 skips py=8 (x1 row 8 = zero pad)

    for (int ch = 0; ch < 2; ++ch) {
        // ---- conv1 via MFMA: 16 co of this chunk, 16-pos tiles ----
        {
            f16x8 a_h = *(const f16x8*)&W1g[(0*32 + ch*16 + m16)*32 + kg*8];
            f16x8 a_l = *(const f16x8*)&W1g[(1*32 + ch*16 + m16)*32 + kg*8];
            float4 b4 = *(const float4*)&c1b[ch*16 + kg*4];
            for (int t = w; t < NT; t += 4) {
                const int py = t >> 1, px = (t & 1)*16 + m16;
                const int row = (kg < 3) ? (2*py + kg) : 0;  // kg=3: A rows zero
                const _Float16* bp0 = &s_u.in[0][row][2*px][0];
                const _Float16* bp1 = &s_u.in[1][row][2*px][0];
                f16x8 b_h, b_l;
                ((uint2*)&b_h)[0] = *(const uint2*)bp0;
                ((uint2*)&b_h)[1] = *(const uint2*)(bp0 + 4);
                ((uint2*)&b_l)[0] = *(const uint2*)bp1;
                ((uint2*)&b_l)[1] = *(const uint2*)(bp1 + 4);
                f32x4 c = {0.f,0.f,0.f,0.f};
                c = __builtin_amdgcn_mfma_f32_16x16x32_f16(a_l, b_h, c, 0, 0, 0);
                c = __builtin_amdgcn_mfma_f32_16x16x32_f16(a_h, b_l, c, 0, 0, 0);
                c = __builtin_amdgcn_mfma_f32_16x16x32_f16(a_h, b_h, c, 0, 0, 0);
                // C: col=l&15=pos, row=kg*4+reg=co -> 4 consecutive ci
                const int xp = px & 1, xq = px >> 1;
                _Float16 hh[4], ll[4];
                #pragma unroll
                for (int r = 0; r < 4; ++r) {
                    float v = c[r] + b4[r];
                    v = fmaxf(v, 0.2f*v);          // leaky
                    _Float16 hi = (_Float16)v;
                    hh[r] = hi; ll[r] = (_Float16)(v - (float)hi);
                }
                *(uint2*)&s_x1[0][kg >> 1][py][xp][xq][(kg & 1)*4] = *(uint2*)hh;
                *(uint2*)&s_x1[1][kg >> 1][py][xp][xq][(kg & 1)*4] = *(uint2*)ll;
            }
        }
        __syncthreads();   // x1 ready

        // ---- conv2 single pass: A(hi,lo) from LDS, B(hi,lo) from global ----
        {
            // per-lane B rows: hi plane (ch*2+0), lo plane (ch*2+1), row co2
            const _Float16* Bg_h = W2h + ((size_t)(ch*2 + 0)*64 + co2)*152 + hf2*8;
            const _Float16* Bg_l = Bg_h + (size_t)64*152;
            #pragma unroll
            for (int tap = 0; tap < 9; ++tap) {
                const int kh = tap/3, kw = tap%3;
                const int xr = 2*px2 + kw;
                const int xp = xr & 1, xq = xr >> 1;
                const int r2 = 2*py2 + kh;
                f16x8 Ah = *(const f16x8*)&s_x1[0][hf2][r2][xp][xq][0];
                f16x8 Al = *(const f16x8*)&s_x1[1][hf2][r2][xp][xq][0];
                f16x8 Bh = *(const f16x8*)&Bg_h[tap*16];
                f16x8 Bl = *(const f16x8*)&Bg_l[tap*16];
                acc = __builtin_amdgcn_mfma_f32_32x32x16_f16(Ah, Bh, acc, 0, 0, 0);
                acc = __builtin_amdgcn_mfma_f32_32x32x16_f16(Al, Bh, acc, 0, 0, 0);
                acc = __builtin_amdgcn_mfma_f32_32x32x16_f16(Ah, Bl, acc, 0, 0, 0);
            }
        }
        __syncthreads();   // chunk done: s_x1 free for rewrite
    }

    // ---- bias + leaky + GAP partial (layout-agnostic: sum all regs) ----
    {
        const float b2 = c2b[co2];
        float s = 0.f;
        #pragma unroll
        for (int r = 0; r < 16; ++r) {
            float v = acc[r] + b2;
            s += fmaxf(v, 0.2f*v);
        }
        s += __shfl_xor(s, 32);
        if (l < 32) s_u.part[w][l] = s;    // s_in dead (barriers in between)
    }
    __syncthreads();
    if (tid < 64) {
        const int nhc = tid >> 5, cl = tid & 31;
        float g = s_u.part[0*2 + nhc][cl] + s_u.part[1*2 + nhc][cl];
        gapp[(size_t)(n*4 + q)*64 + tid] = g;
    }
}

// ---------------------------------------------------------------------------
// kScore: per image (2048 blocks x 128 thr). GAP combine (4 quarters),
// proj, scorer MLP, tanh score.
// ---------------------------------------------------------------------------
__global__ __launch_bounds__(128) void kScore(
    const float* __restrict__ gapp,
    const float* __restrict__ pw,  const float* __restrict__ pb,
    const float* __restrict__ v1w, const float* __restrict__ v1b,
    const float* __restrict__ v2w, const float* __restrict__ v2b,
    const float* __restrict__ v3w, const float* __restrict__ v3b,
    float* __restrict__ feats, float* __restrict__ scores)
{
    __shared__ float s_gap[64], s_f[128], s_h[128], s_red[2];
    const int n = blockIdx.x, tid = threadIdx.x;

    if (tid < 64) {
        const float* gp = &gapp[(size_t)n*256 + tid];
        s_gap[tid] = (gp[0] + gp[64] + gp[128] + gp[192]) * (1.f/256.f);
    }
    __syncthreads();
    {
        float a = pb[tid];
        #pragma unroll 8
        for (int m = 0; m < 64; ++m) a += s_gap[m]*pw[m*128 + tid];
        feats[(size_t)n*128 + tid] = a;
        s_f[tid] = a;
    }
    __syncthreads();
    {
        float a = v1b[tid];
        #pragma unroll 8
        for (int m = 0; m < 128; ++m) a += s_f[m]*v1w[m*128 + tid];
        s_h[tid] = LEAKY(a);
    }
    __syncthreads();
    {
        float a = v2b[tid];
        #pragma unroll 8
        for (int m = 0; m < 128; ++m) a += s_h[m]*v2w[m*128 + tid];
        a = LEAKY(a);
        s_f[tid] = a * v3w[tid];
    }
    __syncthreads();
    {
        float p = s_f[tid];
        #pragma unroll
        for (int off = 32; off; off >>= 1) p += __shfl_xor(p, off);
        if ((tid & 63) == 0) s_red[tid >> 6] = p;
    }
    __syncthreads();
    if (tid == 0) scores[n] = tanhf(s_red[0] + s_red[1] + v3b[0]);
}

// ---------------------------------------------------------------------------
// kArgGather: per-batch argmax (first-index tie-break) + gather feats row
// ---------------------------------------------------------------------------
__global__ __launch_bounds__(128) void kArgGather(
    const float* __restrict__ scores, const float* __restrict__ feats,
    float* __restrict__ res)
{
    __shared__ int s_idx;
    const int b = blockIdx.x, tid = threadIdx.x;
    if (tid < 64) {
        float v = scores[b*64 + tid];
        int   i = tid;
        #pragma unroll
        for (int off = 32; off; off >>= 1) {
            float ov = __shfl_xor(v, off);
            int   oi = __shfl_xor(i, off);
            if (ov > v || (ov == v && oi < i)) { v = ov; i = oi; }
        }
        if (tid == 0) s_idx = i;
    }
    __syncthreads();
    const int idx = s_idx;
    res[b*128 + tid] = feats[((size_t)b*64 + idx)*128 + tid];
}

// ---------------------------------------------------------------------------
// kDecode: decoder (fp32). bid%8 -> same d2 column slice per XCD.
// ---------------------------------------------------------------------------
__global__ __launch_bounds__(512) void kDecode(
    const float* __restrict__ res,
    const float* __restrict__ d1w, const float* __restrict__ d1b,
    const float* __restrict__ d2w, const float* __restrict__ d2b,
    float* __restrict__ out)
{
    __shared__ float s_res[128];
    __shared__ float s_h[512];
    const int bid = blockIdx.x;
    const int b = bid >> 3, ot = bid & 7;
    const int tid = threadIdx.x;

    if (tid < 128) s_res[tid] = res[b*128 + tid];
    __syncthreads();
    {
        float a = d1b[tid];
        #pragma unroll 8
        for (int m = 0; m < 128; ++m) a += s_res[m]*d1w[m*512 + tid];
        s_h[tid] = LEAKY(a);
    }
    __syncthreads();
    const int o = ot*512 + tid;
    float a = d2b[o];
    for (int k = 0; k < 512; k += 4) {
        float4 h4 = *(const float4*)&s_h[k];
        a += h4.x*d2w[(size_t)(k+0)*4096 + o];
        a += h4.y*d2w[(size_t)(k+1)*4096 + o];
        a += h4.z*d2w[(size_t)(k+2)*4096 + o];
        a += h4.w*d2w[(size_t)(k+3)*4096 + o];
    }
    out[(size_t)b*4096 + o] = tanhf(a);
}

// ---------------------------------------------------------------------------
extern "C" void kernel_launch(void* const* d_in, const int* in_sizes, int n_in,
                              void* d_out, int out_size, void* d_ws, size_t ws_size,
                              hipStream_t stream)
{
    const float* texts  = (const float*)d_in[0];
    const float* styles = (const float*)d_in[1];
    const float* c1w = (const float*)d_in[2];
    const float* c1b = (const float*)d_in[3];
    const float* c2w = (const float*)d_in[4];
    const float* c2b = (const float*)d_in[5];
    const float* pw  = (const float*)d_in[6];
    const float* pb  = (const float*)d_in[7];
    const float* v1w = (const float*)d_in[8];
    const float* v1b = (const float*)d_in[9];
    const float* v2w = (const float*)d_in[10];
    const float* v2b = (const float*)d_in[11];
    const float* v3w = (const float*)d_in[12];
    const float* v3b = (const float*)d_in[13];
    const float* d1w = (const float*)d_in[14];
    const float* d1b = (const float*)d_in[15];
    const float* d2w = (const float*)d_in[16];
    const float* d2b = (const float*)d_in[17];

    float* ws     = (float*)d_ws;
    float* feats  = ws + WS_FEATS;
    float* scores = ws + WS_SCORES;
    float* res    = ws + WS_RES;
    float* gapp   = ws + WS_GAPP;

    kPack<<<dim3(16), dim3(256), 0, stream>>>(c1w, c2w, ws);
    kConv<<<dim3(8192), dim3(256), 0, stream>>>(
        texts, styles, c1b, c2b, (const float*)ws, gapp);
    kScore<<<dim3(2048), dim3(128), 0, stream>>>(
        gapp, pw, pb, v1w, v1b, v2w, v2b, v3w, v3b, feats, scores);
    kArgGather<<<dim3(32), dim3(128), 0, stream>>>(scores, feats, res);
    kDecode<<<dim3(256), dim3(512), 0, stream>>>(res, d1w, d1b, d2w, d2b,
                                                 (float*)d_out);
}